// Round 10
// baseline (1276.958 us; speedup 1.0000x reference)
//
#include <hip/hip_runtime.h>
#include <hip/hip_bf16.h>
#include <stdint.h>

#define N_NODES 524288
#define N_EDGES 4194304
#define N_GRAPHS 4096
#define HDIM 32
#define NLAYERS 3
#define KPOOL 30
#define MAXC 1024            // max nodes/graph handled in-LDS in pool (overflow -> fallback)

#define NBUCKET 1024
#define BSHIFT 9             // bucket = dst >> 9
#define NPB 512              // nodes per bucket
#define NCOPY 8              // per-XCD slice copies
#define HIST_SZ (NBUCKET * NCOPY)
#define CAP 6144             // max bucket window held in LDS (mean 4096, sd 64)

typedef unsigned long long ull;

// ---------- histogram of edges per (bucket, xcd-slice) + global degree ----------
__global__ void k_hist(const int* __restrict__ dst, int* __restrict__ ghist,
                       int* __restrict__ deg) {
    __shared__ int lh[NBUCKET];
    int t = threadIdx.x;
    for (int i = t; i < NBUCKET; i += 256) lh[i] = 0;
    __syncthreads();
    int base = blockIdx.x * 2048;
    for (int i = t; i < 2048; i += 256) {
        int d = dst[base + i];
        atomicAdd(&lh[d >> BSHIFT], 1);
        atomicAdd(&deg[d], 1);
    }
    __syncthreads();
    int c = blockIdx.x & 7;
    for (int i = t; i < NBUCKET; i += 256) {
        int v = lh[i];
        if (v) atomicAdd(&ghist[i * NCOPY + c], v);
    }
}

// ---------- dinv = f32(1 / f32(sqrt(deg+1))) -- identical op sequence to reference ----------
__global__ void k_dinv(const int* __restrict__ deg, float* __restrict__ dinv) {
    int n = blockIdx.x * 256 + threadIdx.x;
    if (n < N_NODES) {
        float d = (float)(deg[n] + 1);
        float sq = (float)sqrt((double)d);
        dinv[n] = (float)(1.0 / (double)sq);
    }
}

// ---------- exclusive scan of 8192 counts -> gbase, cur ----------
__global__ void k_scan8k(const int* __restrict__ ghist, int* __restrict__ gbase,
                         int* __restrict__ cur) {
    __shared__ int tmp[256];
    int t = threadIdx.x;
    int loc[32];
    int s = 0;
    for (int k = 0; k < 32; ++k) { loc[k] = ghist[t * 32 + k]; s += loc[k]; }
    tmp[t] = s;
    __syncthreads();
    for (int d = 1; d < 256; d <<= 1) {
        int a = (t >= d) ? tmp[t - d] : 0;
        __syncthreads();
        tmp[t] += a;
        __syncthreads();
    }
    int run = tmp[t] - s;
    for (int k = 0; k < 32; ++k) {
        gbase[t * 32 + k] = run;
        cur[t * 32 + k] = run;
        run += loc[k];
    }
}

// ---------- bin edges into bucket/slice staging: (src<<32)|(dstLocal<<22)|eid ----------
__global__ void k_bin(const int* __restrict__ src, const int* __restrict__ dst,
                      int* __restrict__ cur, ull* __restrict__ stage) {
    int base = blockIdx.x * 2048;
    int c = blockIdx.x & 7;
    int t = threadIdx.x;
    for (int i = t; i < 2048; i += 256) {
        int e = base + i;
        int d = dst[e];
        int b = d >> BSHIFT;
        int pos = atomicAdd(&cur[b * NCOPY + c], 1);
        ull rec = ((ull)(unsigned)src[e] << 32)
                | (unsigned)(((d & (NPB - 1)) << 22) | e);
        stage[pos] = rec;
    }
}

// ---------- per-bucket: offs + LDS-grouped stable csr (eid order) + dinv pack + perm ----------
__global__ void k_build(const ull* __restrict__ stage, const int* __restrict__ gbase,
                        const float* __restrict__ dinv,
                        int* __restrict__ offs, ull* __restrict__ csr2,
                        int* __restrict__ perm) {
    __shared__ ull grp[CAP];
    __shared__ int cnt[NPB];
    __shared__ int sstart[NPB];
    __shared__ int cur[NPB];
    __shared__ int tmp[256];
    int b = blockIdx.x, t = threadIdx.x;
    int s0 = gbase[b * NCOPY];
    int s1 = (b == NBUCKET - 1) ? N_EDGES : gbase[(b + 1) * NCOPY];
    int win = s1 - s0;
    for (int j = t; j < NPB; j += 256) cnt[j] = 0;
    __syncthreads();
    // pass 1: count dstLocal from low words only
    const unsigned* lo32 = (const unsigned*)stage;
    for (int i = t; i < win; i += 256) {
        unsigned k = lo32[2 * (s0 + i)];
        atomicAdd(&cnt[(k >> 22) & (NPB - 1)], 1);
    }
    __syncthreads();
    // scan counts -> segment starts, node offsets
    int j0 = 2 * t, j1 = 2 * t + 1;
    int a0 = cnt[j0], a1 = cnt[j1];
    int s = a0 + a1;
    tmp[t] = s;
    __syncthreads();
    for (int d = 1; d < 256; d <<= 1) {
        int a = (t >= d) ? tmp[t - d] : 0;
        __syncthreads();
        tmp[t] += a;
        __syncthreads();
    }
    int run = tmp[t] - s;
    sstart[j0] = run;      sstart[j1] = run + a0;
    cur[j0] = run;         cur[j1] = run + a0;
    offs[b * NPB + j0] = s0 + run;
    offs[b * NPB + j1] = s0 + run + a0;
    if (b == NBUCKET - 1 && t == 255) offs[N_NODES] = N_EDGES;
    __syncthreads();

    if (win <= CAP) {
        // pass 2: re-read window, group into LDS
        for (int i = t; i < win; i += 256) {
            ull v = stage[s0 + i];
            unsigned k = (unsigned)v;
            int pos = atomicAdd(&cur[(k >> 22) & (NPB - 1)], 1);
            grp[pos] = v;
        }
        __syncthreads();
        // per-node insertion sort by low word (== eid order within a node)
        for (int jj = 0; jj < 2; ++jj) {
            int j = 2 * t + jj;
            int beg = sstart[j], end = beg + cnt[j];
            for (int i = beg + 1; i < end; ++i) {
                ull v = grp[i];
                unsigned kv = (unsigned)v;
                int q = i - 1;
                while (q >= beg && (unsigned)grp[q] > kv) { grp[q + 1] = grp[q]; --q; }
                grp[q + 1] = v;
            }
        }
        __syncthreads();
        // write-out with folded dinv pack (4-deep MLP on the dinv gather)
        int i = t;
        for (; i + 768 < win; i += 1024) {
            ull v0 = grp[i], v1 = grp[i + 256], v2 = grp[i + 512], v3 = grp[i + 768];
            float d0 = dinv[(int)(v0 >> 32)];
            float d1 = dinv[(int)(v1 >> 32)];
            float d2 = dinv[(int)(v2 >> 32)];
            float d3 = dinv[(int)(v3 >> 32)];
            csr2[s0 + i]       = (v0 & 0xffffffff00000000ull) | (unsigned)__float_as_uint(d0);
            csr2[s0 + i + 256] = (v1 & 0xffffffff00000000ull) | (unsigned)__float_as_uint(d1);
            csr2[s0 + i + 512] = (v2 & 0xffffffff00000000ull) | (unsigned)__float_as_uint(d2);
            csr2[s0 + i + 768] = (v3 & 0xffffffff00000000ull) | (unsigned)__float_as_uint(d3);
        }
        for (; i < win; i += 256) {
            ull v = grp[i];
            float dv = dinv[(int)(v >> 32)];
            csr2[s0 + i] = (v & 0xffffffff00000000ull) | (unsigned)__float_as_uint(dv);
        }
    } else {
        // fallback (never triggers for this input): global group + sort + pack
        for (int i = t; i < win; i += 256) {
            ull v = stage[s0 + i];
            unsigned k = (unsigned)v;
            int pos = s0 + atomicAdd(&cur[(k >> 22) & (NPB - 1)], 1);
            csr2[pos] = v;
        }
        __syncthreads();
        for (int jj = 0; jj < 2; ++jj) {
            int j = 2 * t + jj;
            int beg = s0 + sstart[j], end = beg + cnt[j];
            for (int i = beg + 1; i < end; ++i) {
                ull v = csr2[i];
                unsigned kv = (unsigned)v;
                int q = i - 1;
                while (q >= beg && (unsigned)csr2[q] > kv) { csr2[q + 1] = csr2[q]; --q; }
                csr2[q + 1] = v;
            }
        }
        __syncthreads();
        for (int i = t; i < win; i += 256) {
            ull v = csr2[s0 + i];
            float dv = dinv[(int)(v >> 32)];
            csr2[s0 + i] = (v & 0xffffffff00000000ull) | (unsigned)__float_as_uint(dv);
        }
    }
    __syncthreads();
    // degree-paired schedule: rank nodes by (deg, idx); perm[rank] = node
    for (int jj = 0; jj < 2; ++jj) {
        int j = 2 * t + jj;
        int dj = cnt[j];
        int r = 0;
        for (int k = 0; k < NPB; ++k) {
            int dk = cnt[k];
            r += (dk < dj) || (dk == dj && k < j);
        }
        perm[b * NPB + r] = b * NPB + j;
    }
}

// ---------- rs = f32(1 / f32(sqrt(f32(rvar + 1e-5)))) ----------
__global__ void k_bnprep(const float* __restrict__ rvar, float* __restrict__ rs) {
    int i = threadIdx.x;
    if (i < NLAYERS * HDIM) {
        float rv = __fadd_rn(rvar[i], 1e-5f);
        float sq = (float)sqrt((double)rv);
        rs[i] = (float)(1.0 / (double)sq);
    }
}

// ---------- fused embed + matmul layer0 ----------
__global__ void k_embed_mm(const int* __restrict__ xz, const float* __restrict__ emb,
                           const float* __restrict__ Wc, float* __restrict__ h) {
    __shared__ float Wl[HDIM * HDIM];
    __shared__ float xt[256];
    int t = threadIdx.x;
    int base = blockIdx.x * 256;
    for (int i = t; i < HDIM * HDIM; i += 256) Wl[i] = Wc[i];
    {
        int gid = base + t;
        int n = gid >> 5, c = gid & 31;
        xt[t] = emb[xz[n] * HDIM + c];
    }
    __syncthreads();
    int nl = t >> 5, c = t & 31;
    float acc = 0.0f;
#pragma unroll
    for (int k = 0; k < HDIM; ++k) acc = __fmaf_rn(xt[nl * HDIM + k], Wl[k * HDIM + c], acc);
    h[base + t] = acc;
}

// ---------- agg phase: strict f32 op order, 8-deep software pipeline ----------
__device__ __forceinline__ float agg_phase(const float* __restrict__ h,
                                           const float* __restrict__ dinv,
                                           const int* __restrict__ offs,
                                           const ull* __restrict__ csr2,
                                           const float* __restrict__ bc,
                                           const float* __restrict__ rmean,
                                           const float* __restrict__ rs,
                                           const float* __restrict__ gamma,
                                           const float* __restrict__ beta,
                                           int n, int c) {
    float di = dinv[n];
    float hself = h[n * HDIM + c];        // hoisted: overlaps with edge loop
    float accE = 0.0f;  // np.add.at: sequential in edge-id order
    int beg = offs[n], end = offs[n + 1];
    int i = beg;
    for (; i + 8 <= end; i += 8) {
        ull r0 = csr2[i];
        ull r1 = csr2[i + 1];
        ull r2 = csr2[i + 2];
        ull r3 = csr2[i + 3];
        ull r4 = csr2[i + 4];
        ull r5 = csr2[i + 5];
        ull r6 = csr2[i + 6];
        ull r7 = csr2[i + 7];
        float h0 = h[(int)(r0 >> 32) * HDIM + c];
        float h1 = h[(int)(r1 >> 32) * HDIM + c];
        float h2 = h[(int)(r2 >> 32) * HDIM + c];
        float h3 = h[(int)(r3 >> 32) * HDIM + c];
        float h4 = h[(int)(r4 >> 32) * HDIM + c];
        float h5 = h[(int)(r5 >> 32) * HDIM + c];
        float h6 = h[(int)(r6 >> 32) * HDIM + c];
        float h7 = h[(int)(r7 >> 32) * HDIM + c];
        accE = __fadd_rn(accE, __fmul_rn(h0, __fmul_rn(__uint_as_float((unsigned)r0), di)));
        accE = __fadd_rn(accE, __fmul_rn(h1, __fmul_rn(__uint_as_float((unsigned)r1), di)));
        accE = __fadd_rn(accE, __fmul_rn(h2, __fmul_rn(__uint_as_float((unsigned)r2), di)));
        accE = __fadd_rn(accE, __fmul_rn(h3, __fmul_rn(__uint_as_float((unsigned)r3), di)));
        accE = __fadd_rn(accE, __fmul_rn(h4, __fmul_rn(__uint_as_float((unsigned)r4), di)));
        accE = __fadd_rn(accE, __fmul_rn(h5, __fmul_rn(__uint_as_float((unsigned)r5), di)));
        accE = __fadd_rn(accE, __fmul_rn(h6, __fmul_rn(__uint_as_float((unsigned)r6), di)));
        accE = __fadd_rn(accE, __fmul_rn(h7, __fmul_rn(__uint_as_float((unsigned)r7), di)));
    }
    for (; i + 4 <= end; i += 4) {
        ull r0 = csr2[i];
        ull r1 = csr2[i + 1];
        ull r2 = csr2[i + 2];
        ull r3 = csr2[i + 3];
        float h0 = h[(int)(r0 >> 32) * HDIM + c];
        float h1 = h[(int)(r1 >> 32) * HDIM + c];
        float h2 = h[(int)(r2 >> 32) * HDIM + c];
        float h3 = h[(int)(r3 >> 32) * HDIM + c];
        accE = __fadd_rn(accE, __fmul_rn(h0, __fmul_rn(__uint_as_float((unsigned)r0), di)));
        accE = __fadd_rn(accE, __fmul_rn(h1, __fmul_rn(__uint_as_float((unsigned)r1), di)));
        accE = __fadd_rn(accE, __fmul_rn(h2, __fmul_rn(__uint_as_float((unsigned)r2), di)));
        accE = __fadd_rn(accE, __fmul_rn(h3, __fmul_rn(__uint_as_float((unsigned)r3), di)));
    }
    for (; i < end; ++i) {
        ull r = csr2[i];
        float hv = h[(int)(r >> 32) * HDIM + c];
        float dv = __uint_as_float((unsigned)r);
        accE = __fadd_rn(accE, __fmul_rn(hv, __fmul_rn(dv, di)));
    }
    float sn = __fmul_rn(di, di);
    float t1 = __fmul_rn(hself, sn);
    float a2 = __fadd_rn(accE, t1);
    float a3 = __fadd_rn(a2, bc[c]);
    float tt = __fsub_rn(a3, rmean[c]);
    float u  = __fmul_rn(tt, rs[c]);
    float v  = __fmul_rn(u, gamma[c]);
    float xn = __fadd_rn(v, beta[c]);
    return (xn > 0.0f) ? xn : 0.0f;
}

// ---------- fused agg(BN,ReLU) + next-layer matmul, degree-paired schedule ----------
__global__ void k_agg_mm(const float* __restrict__ h, const float* __restrict__ dinv,
                         const int* __restrict__ offs, const ull* __restrict__ csr2,
                         const int* __restrict__ perm,
                         const float* __restrict__ bc, const float* __restrict__ rmean,
                         const float* __restrict__ rs, const float* __restrict__ gamma,
                         const float* __restrict__ beta,
                         const float* __restrict__ Wnext, float* __restrict__ hout) {
    __shared__ float Wl[HDIM * HDIM];
    __shared__ float xt[256];
    __shared__ int nodes[8];
    int t = threadIdx.x;
    for (int i = t; i < HDIM * HDIM; i += 256) Wl[i] = Wnext[i];
    if (t < 8) nodes[t] = perm[blockIdx.x * 8 + t];
    __syncthreads();
    int slot = t >> 5, c = t & 31;
    int n = nodes[slot];
    xt[t] = agg_phase(h, dinv, offs, csr2, bc, rmean, rs, gamma, beta, n, c);
    __syncthreads();
    float acc = 0.0f;
#pragma unroll
    for (int k = 0; k < HDIM; ++k) acc = __fmaf_rn(xt[slot * HDIM + k], Wl[k * HDIM + c], acc);
    hout[n * HDIM + c] = acc;
}

// ---------- last agg: also emit dense channel-31 array for the sort-pool ----------
__global__ void k_agg_last(const float* __restrict__ h, const float* __restrict__ dinv,
                           const int* __restrict__ offs, const ull* __restrict__ csr2,
                           const int* __restrict__ perm,
                           const float* __restrict__ bc, const float* __restrict__ rmean,
                           const float* __restrict__ rs, const float* __restrict__ gamma,
                           const float* __restrict__ beta, float* __restrict__ xout,
                           float* __restrict__ lastc) {
    __shared__ int nodes[8];
    int t = threadIdx.x;
    if (t < 8) nodes[t] = perm[blockIdx.x * 8 + t];
    __syncthreads();
    int slot = t >> 5, c = t & 31;
    int n = nodes[slot];
    float v = agg_phase(h, dinv, offs, csr2, bc, rmean, rs, gamma, beta, n, c);
    xout[n * HDIM + c] = v;
    if (c == 31) lastc[n] = v;
}

// ---------- per-graph starts ----------
__global__ void k_starts(const int* __restrict__ batch, int* __restrict__ start) {
    int n = blockIdx.x * 256 + threadIdx.x;
    if (n >= N_NODES) return;
    int bn = batch[n];
    int bp = (n == 0) ? -1 : batch[n - 1];
    for (int g = bp + 1; g <= bn; ++g) start[g] = n;
    if (n == N_NODES - 1) {
        for (int g = bn + 1; g <= N_GRAPHS; ++g) start[g] = N_NODES;
    }
}

// ---------- sort-pool (keys cached in LDS) + MLP (f64 accumulate) ----------
__global__ void k_pool_mlp(const float* __restrict__ x, const float* __restrict__ lastc,
                           const int* __restrict__ start,
                           const float* __restrict__ W1, const float* __restrict__ b1,
                           const float* __restrict__ W2, const float* __restrict__ b2,
                           const float* __restrict__ W3, const float* __restrict__ b3,
                           float* __restrict__ out) {
    int g = blockIdx.x;
    int t = threadIdx.x;  // 64 threads = 1 wave
    int s = start[g], e = start[g + 1];
    int cnt = e - s;

    __shared__ ull keys[MAXC];
    __shared__ int sel[KPOOL];
    __shared__ float pl[KPOOL * HDIM];
    __shared__ double part[64];
    __shared__ double h1[HDIM];
    __shared__ double h2[HDIM / 2];

    bool inlds = (cnt <= MAXC);
    if (inlds) {
        for (int i = t; i < cnt; i += 64) {
            int n = s + i;
            keys[i] = ((ull)__float_as_uint(lastc[n]) << 32) | (unsigned int)(~n);
        }
    }
    __syncthreads();

    ull prev = ~0ull;
    for (int k = 0; k < KPOOL; ++k) {
        if (k < cnt) {
            ull best = 0ull;
            if (inlds) {
                for (int i = t; i < cnt; i += 64) {
                    ull key = keys[i];
                    if (key < prev && key > best) best = key;
                }
            } else {
                for (int n = s + t; n < e; n += 64) {
                    ull key = ((ull)__float_as_uint(lastc[n]) << 32) | (unsigned int)(~n);
                    if (key < prev && key > best) best = key;
                }
            }
            for (int off = 32; off; off >>= 1) {
                ull o = __shfl_down(best, off);
                if (o > best) best = o;
            }
            best = __shfl(best, 0);
            prev = best;
            if (t == 0) sel[k] = (int)(~((unsigned int)(best & 0xffffffffull)));
        } else {
            if (t == 0) sel[k] = -1;
        }
    }
    __syncthreads();

    for (int idx = t; idx < KPOOL * HDIM; idx += 64) {
        int k = idx >> 5, c = idx & 31;
        int n = sel[k];
        pl[idx] = (n >= 0) ? x[n * HDIM + c] : 0.0f;
    }
    __syncthreads();

    {
        int j = t & 31;
        int half = t >> 5;
        double acc = 0.0;
        int r0 = half * (KPOOL * HDIM / 2);
        for (int r = r0; r < r0 + KPOOL * HDIM / 2; ++r)
            acc += (double)pl[r] * (double)W1[r * HDIM + j];
        part[t] = acc;
    }
    __syncthreads();
    if (t < HDIM) {
        double v = part[t] + part[t + 32] + (double)b1[t];
        h1[t] = (v > 0.0) ? v : 0.0;
    }
    __syncthreads();

    if (t < HDIM / 2) {
        double a2 = (double)b2[t];
        for (int i = 0; i < HDIM; ++i) a2 += h1[i] * (double)W2[i * (HDIM / 2) + t];
        h2[t] = (a2 > 0.0) ? a2 : 0.0;
    }
    __syncthreads();

    if (t == 0) {
        double o = (double)b3[0];
        for (int i = 0; i < HDIM / 2; ++i) o += h2[i] * (double)W3[i];
        out[g] = (float)o;
    }
}

extern "C" void kernel_launch(void* const* d_in, const int* in_sizes, int n_in,
                              void* d_out, int out_size, void* d_ws, size_t ws_size,
                              hipStream_t stream) {
    const int*   xz    = (const int*)d_in[0];
    const int*   src   = (const int*)d_in[1];            // edge_index[0]
    const int*   dst   = (const int*)d_in[1] + N_EDGES;  // edge_index[1]
    const int*   batch = (const int*)d_in[2];
    const float* emb   = (const float*)d_in[3];
    const float* Wc    = (const float*)d_in[4];
    const float* bc    = (const float*)d_in[5];
    const float* gamma = (const float*)d_in[6];
    const float* beta  = (const float*)d_in[7];
    const float* rmean = (const float*)d_in[8];
    const float* rvar  = (const float*)d_in[9];
    const float* W1    = (const float*)d_in[10];
    const float* b1    = (const float*)d_in[11];
    const float* W2    = (const float*)d_in[12];
    const float* b2    = (const float*)d_in[13];
    const float* W3    = (const float*)d_in[14];
    const float* b3    = (const float*)d_in[15];
    float* out = (float*)d_out;

    // workspace carve-up (256B aligned). Total ~211 MB.
    char* p = (char*)d_ws;
    auto carve = [&](size_t bytes) {
        void* q = (void*)p;
        p += (bytes + 255) & ~size_t(255);
        return q;
    };
    int*   ghist = (int*)carve(HIST_SZ * 4);
    int*   gbase = (int*)carve(HIST_SZ * 4);
    int*   cur   = (int*)carve(HIST_SZ * 4);
    int*   deg   = (int*)carve(N_NODES * 4);
    ull*   stage = (ull*)carve((size_t)N_EDGES * 8);
    ull*   csr2  = (ull*)carve((size_t)N_EDGES * 8);
    float* dinv  = (float*)carve(N_NODES * 4);
    int*   offs  = (int*)carve((N_NODES + 1) * 4);
    int*   permB = (int*)carve(N_NODES * 4);
    int*   start = (int*)carve((N_GRAPHS + 1) * 4);
    float* rs    = (float*)carve(NLAYERS * HDIM * 4);
    float* lastc = (float*)carve(N_NODES * 4);
    float* bufA  = (float*)carve((size_t)N_NODES * HDIM * 4);
    float* bufB  = (float*)carve((size_t)N_NODES * HDIM * 4);

    hipMemsetAsync(ghist, 0, HIST_SZ * 4, stream);
    hipMemsetAsync(deg, 0, N_NODES * 4, stream);

    k_hist<<<N_EDGES / 2048, 256, 0, stream>>>(dst, ghist, deg);
    k_scan8k<<<1, 256, 0, stream>>>(ghist, gbase, cur);
    k_dinv<<<N_NODES / 256, 256, 0, stream>>>(deg, dinv);
    k_bin<<<N_EDGES / 2048, 256, 0, stream>>>(src, dst, cur, stage);
    k_build<<<NBUCKET, 256, 0, stream>>>(stage, gbase, dinv, offs, csr2, permB);
    k_bnprep<<<1, 128, 0, stream>>>(rvar, rs);
    k_starts<<<N_NODES / 256, 256, 0, stream>>>(batch, start);

    const int NG = (N_NODES * HDIM) / 256;
    k_embed_mm<<<NG, 256, 0, stream>>>(xz, emb, Wc + 0 * HDIM * HDIM, bufA);
    k_agg_mm<<<N_NODES / 8, 256, 0, stream>>>(bufA, dinv, offs, csr2, permB,
        bc + 0 * HDIM, rmean + 0 * HDIM, rs + 0 * HDIM, gamma + 0 * HDIM, beta + 0 * HDIM,
        Wc + 1 * HDIM * HDIM, bufB);
    k_agg_mm<<<N_NODES / 8, 256, 0, stream>>>(bufB, dinv, offs, csr2, permB,
        bc + 1 * HDIM, rmean + 1 * HDIM, rs + 1 * HDIM, gamma + 1 * HDIM, beta + 1 * HDIM,
        Wc + 2 * HDIM * HDIM, bufA);
    k_agg_last<<<N_NODES / 8, 256, 0, stream>>>(bufA, dinv, offs, csr2, permB,
        bc + 2 * HDIM, rmean + 2 * HDIM, rs + 2 * HDIM, gamma + 2 * HDIM, beta + 2 * HDIM,
        bufB, lastc);

    k_pool_mlp<<<N_GRAPHS, 64, 0, stream>>>(bufB, lastc, start, W1, b1, W2, b2, W3, b3, out);
}

// Round 11
// 1145.482 us; speedup vs baseline: 1.1148x; 1.1148x over previous
//
#include <hip/hip_runtime.h>
#include <hip/hip_bf16.h>
#include <stdint.h>

#define N_NODES 524288
#define N_EDGES 4194304
#define N_GRAPHS 4096
#define HDIM 32
#define NLAYERS 3
#define KPOOL 30
#define MAXC 1024            // max nodes/graph handled in-LDS in pool (overflow -> fallback)

#define NBUCKET 1024
#define BSHIFT 9             // bucket = dst >> 9
#define NPB 512              // nodes per bucket
#define NCOPY 8              // per-XCD slice copies
#define HIST_SZ (NBUCKET * NCOPY)
#define CAP 6144             // max bucket window held in LDS (mean 4096, sd ~64)

typedef unsigned long long ull;

// ---------- histogram of edges per (bucket, xcd-slice) ----------
__global__ void k_hist(const int* __restrict__ dst, int* __restrict__ ghist) {
    __shared__ int lh[NBUCKET];
    int t = threadIdx.x;
    for (int i = t; i < NBUCKET; i += 256) lh[i] = 0;
    __syncthreads();
    int base = blockIdx.x * 2048;
    for (int i = t; i < 2048; i += 256) {
        int d = dst[base + i];
        atomicAdd(&lh[d >> BSHIFT], 1);
    }
    __syncthreads();
    int c = blockIdx.x & 7;
    for (int i = t; i < NBUCKET; i += 256) {
        int v = lh[i];
        if (v) atomicAdd(&ghist[i * NCOPY + c], v);
    }
}

// ---------- exclusive scan of 8192 counts -> gbase, cur ----------
__global__ void k_scan8k(const int* __restrict__ ghist, int* __restrict__ gbase,
                         int* __restrict__ cur) {
    __shared__ int tmp[256];
    int t = threadIdx.x;
    int loc[32];
    int s = 0;
    for (int k = 0; k < 32; ++k) { loc[k] = ghist[t * 32 + k]; s += loc[k]; }
    tmp[t] = s;
    __syncthreads();
    for (int d = 1; d < 256; d <<= 1) {
        int a = (t >= d) ? tmp[t - d] : 0;
        __syncthreads();
        tmp[t] += a;
        __syncthreads();
    }
    int run = tmp[t] - s;
    for (int k = 0; k < 32; ++k) {
        gbase[t * 32 + k] = run;
        cur[t * 32 + k] = run;
        run += loc[k];
    }
}

// ---------- bin edges into bucket/slice staging: (src<<32)|(dstLocal<<22)|eid ----------
__global__ void k_bin(const int* __restrict__ src, const int* __restrict__ dst,
                      int* __restrict__ cur, ull* __restrict__ stage) {
    int base = blockIdx.x * 2048;
    int c = blockIdx.x & 7;
    int t = threadIdx.x;
    for (int i = t; i < 2048; i += 256) {
        int e = base + i;
        int d = dst[e];
        int b = d >> BSHIFT;
        int pos = atomicAdd(&cur[b * NCOPY + c], 1);
        ull rec = ((ull)(unsigned)src[e] << 32)
                | (unsigned)(((d & (NPB - 1)) << 22) | e);
        stage[pos] = rec;
    }
}

// ---------- per-bucket: dinv (from counts) + offs + LDS-grouped stable csr + perm ----------
__global__ void k_build(const ull* __restrict__ stage, const int* __restrict__ gbase,
                        float* __restrict__ dinv,
                        int* __restrict__ offs, ull* __restrict__ csr2,
                        int* __restrict__ perm) {
    __shared__ ull grp[CAP];
    __shared__ int cnt[NPB];
    __shared__ int sstart[NPB];
    __shared__ int cur[NPB];
    __shared__ int tmp[256];
    int b = blockIdx.x, t = threadIdx.x;
    int s0 = gbase[b * NCOPY];
    int s1 = (b == NBUCKET - 1) ? N_EDGES : gbase[(b + 1) * NCOPY];
    int win = s1 - s0;
    for (int j = t; j < NPB; j += 256) cnt[j] = 0;
    __syncthreads();
    // pass 1: count dstLocal from low words only
    const unsigned* lo32 = (const unsigned*)stage;
    for (int i = t; i < win; i += 256) {
        unsigned k = lo32[2 * (s0 + i)];
        atomicAdd(&cnt[(k >> 22) & (NPB - 1)], 1);
    }
    __syncthreads();
    // scan counts -> segment starts, node offsets; dinv from counts (cnt == in-degree)
    int j0 = 2 * t, j1 = 2 * t + 1;
    int a0 = cnt[j0], a1 = cnt[j1];
    {
        // dinv = f32(1 / f32(sqrt(deg+1)))  (identical op sequence to reference)
        float d0 = (float)(a0 + 1);
        float q0 = (float)sqrt((double)d0);
        dinv[b * NPB + j0] = (float)(1.0 / (double)q0);
        float d1 = (float)(a1 + 1);
        float q1 = (float)sqrt((double)d1);
        dinv[b * NPB + j1] = (float)(1.0 / (double)q1);
    }
    int s = a0 + a1;
    tmp[t] = s;
    __syncthreads();
    for (int d = 1; d < 256; d <<= 1) {
        int a = (t >= d) ? tmp[t - d] : 0;
        __syncthreads();
        tmp[t] += a;
        __syncthreads();
    }
    int run = tmp[t] - s;
    sstart[j0] = run;      sstart[j1] = run + a0;
    cur[j0] = run;         cur[j1] = run + a0;
    offs[b * NPB + j0] = s0 + run;
    offs[b * NPB + j1] = s0 + run + a0;
    if (b == NBUCKET - 1 && t == 255) offs[N_NODES] = N_EDGES;
    __syncthreads();

    if (win <= CAP) {
        // pass 2: re-read window, group into LDS
        for (int i = t; i < win; i += 256) {
            ull v = stage[s0 + i];
            unsigned k = (unsigned)v;
            int pos = atomicAdd(&cur[(k >> 22) & (NPB - 1)], 1);
            grp[pos] = v;
        }
        __syncthreads();
        // per-node insertion sort by low word (== eid order within a node)
        for (int jj = 0; jj < 2; ++jj) {
            int j = 2 * t + jj;
            int beg = sstart[j], end = beg + cnt[j];
            for (int i = beg + 1; i < end; ++i) {
                ull v = grp[i];
                unsigned kv = (unsigned)v;
                int q = i - 1;
                while (q >= beg && (unsigned)grp[q] > kv) { grp[q + 1] = grp[q]; --q; }
                grp[q + 1] = v;
            }
        }
        __syncthreads();
        for (int i = t; i < win; i += 256) csr2[s0 + i] = grp[i];
    } else {
        // fallback (never triggers for this input): global group + sort
        for (int i = t; i < win; i += 256) {
            ull v = stage[s0 + i];
            unsigned k = (unsigned)v;
            int pos = s0 + atomicAdd(&cur[(k >> 22) & (NPB - 1)], 1);
            csr2[pos] = v;
        }
        __syncthreads();
        for (int jj = 0; jj < 2; ++jj) {
            int j = 2 * t + jj;
            int beg = s0 + sstart[j], end = beg + cnt[j];
            for (int i = beg + 1; i < end; ++i) {
                ull v = csr2[i];
                unsigned kv = (unsigned)v;
                int q = i - 1;
                while (q >= beg && (unsigned)csr2[q] > kv) { csr2[q + 1] = csr2[q]; --q; }
                csr2[q + 1] = v;
            }
        }
    }
    __syncthreads();
    // degree-paired schedule: rank nodes by (deg, idx); perm[rank] = node
    for (int jj = 0; jj < 2; ++jj) {
        int j = 2 * t + jj;
        int dj = cnt[j];
        int r = 0;
        for (int k = 0; k < NPB; ++k) {
            int dk = cnt[k];
            r += (dk < dj) || (dk == dj && k < j);
        }
        perm[b * NPB + r] = b * NPB + j;
    }
}

// ---------- pack dinv[src] into the (now dead) low word of each record ----------
__global__ void k_pack(const float* __restrict__ dinv, ull* __restrict__ csr2) {
    int i = blockIdx.x * 256 + threadIdx.x;
    if (i < N_EDGES) {
        ull r = csr2[i];
        int s = (int)(r >> 32);
        csr2[i] = (r & 0xffffffff00000000ull) | (unsigned)__float_as_uint(dinv[s]);
    }
}

// ---------- rs = f32(1 / f32(sqrt(f32(rvar + 1e-5)))) ----------
__global__ void k_bnprep(const float* __restrict__ rvar, float* __restrict__ rs) {
    int i = threadIdx.x;
    if (i < NLAYERS * HDIM) {
        float rv = __fadd_rn(rvar[i], 1e-5f);
        float sq = (float)sqrt((double)rv);
        rs[i] = (float)(1.0 / (double)sq);
    }
}

// ---------- fused embed + matmul layer0 ----------
__global__ void k_embed_mm(const int* __restrict__ xz, const float* __restrict__ emb,
                           const float* __restrict__ Wc, float* __restrict__ h) {
    __shared__ float Wl[HDIM * HDIM];
    __shared__ float xt[256];
    int t = threadIdx.x;
    int base = blockIdx.x * 256;
    for (int i = t; i < HDIM * HDIM; i += 256) Wl[i] = Wc[i];
    {
        int gid = base + t;
        int n = gid >> 5, c = gid & 31;
        xt[t] = emb[xz[n] * HDIM + c];
    }
    __syncthreads();
    int nl = t >> 5, c = t & 31;
    float acc = 0.0f;
#pragma unroll
    for (int k = 0; k < HDIM; ++k) acc = __fmaf_rn(xt[nl * HDIM + k], Wl[k * HDIM + c], acc);
    h[base + t] = acc;
}

// ---------- agg phase: strict f32 op order, 8-deep software pipeline ----------
__device__ __forceinline__ float agg_phase(const float* __restrict__ h,
                                           const float* __restrict__ dinv,
                                           const int* __restrict__ offs,
                                           const ull* __restrict__ csr2,
                                           const float* __restrict__ bc,
                                           const float* __restrict__ rmean,
                                           const float* __restrict__ rs,
                                           const float* __restrict__ gamma,
                                           const float* __restrict__ beta,
                                           int n, int c) {
    float di = dinv[n];
    float hself = h[n * HDIM + c];        // hoisted: overlaps with edge loop
    float accE = 0.0f;  // np.add.at: sequential in edge-id order
    int beg = offs[n], end = offs[n + 1];
    int i = beg;
    for (; i + 8 <= end; i += 8) {
        ull r0 = csr2[i];
        ull r1 = csr2[i + 1];
        ull r2 = csr2[i + 2];
        ull r3 = csr2[i + 3];
        ull r4 = csr2[i + 4];
        ull r5 = csr2[i + 5];
        ull r6 = csr2[i + 6];
        ull r7 = csr2[i + 7];
        float h0 = h[(int)(r0 >> 32) * HDIM + c];
        float h1 = h[(int)(r1 >> 32) * HDIM + c];
        float h2 = h[(int)(r2 >> 32) * HDIM + c];
        float h3 = h[(int)(r3 >> 32) * HDIM + c];
        float h4 = h[(int)(r4 >> 32) * HDIM + c];
        float h5 = h[(int)(r5 >> 32) * HDIM + c];
        float h6 = h[(int)(r6 >> 32) * HDIM + c];
        float h7 = h[(int)(r7 >> 32) * HDIM + c];
        accE = __fadd_rn(accE, __fmul_rn(h0, __fmul_rn(__uint_as_float((unsigned)r0), di)));
        accE = __fadd_rn(accE, __fmul_rn(h1, __fmul_rn(__uint_as_float((unsigned)r1), di)));
        accE = __fadd_rn(accE, __fmul_rn(h2, __fmul_rn(__uint_as_float((unsigned)r2), di)));
        accE = __fadd_rn(accE, __fmul_rn(h3, __fmul_rn(__uint_as_float((unsigned)r3), di)));
        accE = __fadd_rn(accE, __fmul_rn(h4, __fmul_rn(__uint_as_float((unsigned)r4), di)));
        accE = __fadd_rn(accE, __fmul_rn(h5, __fmul_rn(__uint_as_float((unsigned)r5), di)));
        accE = __fadd_rn(accE, __fmul_rn(h6, __fmul_rn(__uint_as_float((unsigned)r6), di)));
        accE = __fadd_rn(accE, __fmul_rn(h7, __fmul_rn(__uint_as_float((unsigned)r7), di)));
    }
    for (; i + 4 <= end; i += 4) {
        ull r0 = csr2[i];
        ull r1 = csr2[i + 1];
        ull r2 = csr2[i + 2];
        ull r3 = csr2[i + 3];
        float h0 = h[(int)(r0 >> 32) * HDIM + c];
        float h1 = h[(int)(r1 >> 32) * HDIM + c];
        float h2 = h[(int)(r2 >> 32) * HDIM + c];
        float h3 = h[(int)(r3 >> 32) * HDIM + c];
        accE = __fadd_rn(accE, __fmul_rn(h0, __fmul_rn(__uint_as_float((unsigned)r0), di)));
        accE = __fadd_rn(accE, __fmul_rn(h1, __fmul_rn(__uint_as_float((unsigned)r1), di)));
        accE = __fadd_rn(accE, __fmul_rn(h2, __fmul_rn(__uint_as_float((unsigned)r2), di)));
        accE = __fadd_rn(accE, __fmul_rn(h3, __fmul_rn(__uint_as_float((unsigned)r3), di)));
    }
    for (; i < end; ++i) {
        ull r = csr2[i];
        float hv = h[(int)(r >> 32) * HDIM + c];
        float dv = __uint_as_float((unsigned)r);
        accE = __fadd_rn(accE, __fmul_rn(hv, __fmul_rn(dv, di)));
    }
    float sn = __fmul_rn(di, di);
    float t1 = __fmul_rn(hself, sn);
    float a2 = __fadd_rn(accE, t1);
    float a3 = __fadd_rn(a2, bc[c]);
    float tt = __fsub_rn(a3, rmean[c]);
    float u  = __fmul_rn(tt, rs[c]);
    float v  = __fmul_rn(u, gamma[c]);
    float xn = __fadd_rn(v, beta[c]);
    return (xn > 0.0f) ? xn : 0.0f;
}

// ---------- fused agg(BN,ReLU) + next-layer matmul, degree-paired schedule ----------
__global__ void k_agg_mm(const float* __restrict__ h, const float* __restrict__ dinv,
                         const int* __restrict__ offs, const ull* __restrict__ csr2,
                         const int* __restrict__ perm,
                         const float* __restrict__ bc, const float* __restrict__ rmean,
                         const float* __restrict__ rs, const float* __restrict__ gamma,
                         const float* __restrict__ beta,
                         const float* __restrict__ Wnext, float* __restrict__ hout) {
    __shared__ float Wl[HDIM * HDIM];
    __shared__ float xt[256];
    __shared__ int nodes[8];
    int t = threadIdx.x;
    for (int i = t; i < HDIM * HDIM; i += 256) Wl[i] = Wnext[i];
    if (t < 8) nodes[t] = perm[blockIdx.x * 8 + t];
    __syncthreads();
    int slot = t >> 5, c = t & 31;
    int n = nodes[slot];
    xt[t] = agg_phase(h, dinv, offs, csr2, bc, rmean, rs, gamma, beta, n, c);
    __syncthreads();
    float acc = 0.0f;
#pragma unroll
    for (int k = 0; k < HDIM; ++k) acc = __fmaf_rn(xt[slot * HDIM + k], Wl[k * HDIM + c], acc);
    hout[n * HDIM + c] = acc;
}

// ---------- last agg: also emit dense channel-31 array for the sort-pool ----------
__global__ void k_agg_last(const float* __restrict__ h, const float* __restrict__ dinv,
                           const int* __restrict__ offs, const ull* __restrict__ csr2,
                           const int* __restrict__ perm,
                           const float* __restrict__ bc, const float* __restrict__ rmean,
                           const float* __restrict__ rs, const float* __restrict__ gamma,
                           const float* __restrict__ beta, float* __restrict__ xout,
                           float* __restrict__ lastc) {
    __shared__ int nodes[8];
    int t = threadIdx.x;
    if (t < 8) nodes[t] = perm[blockIdx.x * 8 + t];
    __syncthreads();
    int slot = t >> 5, c = t & 31;
    int n = nodes[slot];
    float v = agg_phase(h, dinv, offs, csr2, bc, rmean, rs, gamma, beta, n, c);
    xout[n * HDIM + c] = v;
    if (c == 31) lastc[n] = v;
}

// ---------- per-graph starts ----------
__global__ void k_starts(const int* __restrict__ batch, int* __restrict__ start) {
    int n = blockIdx.x * 256 + threadIdx.x;
    if (n >= N_NODES) return;
    int bn = batch[n];
    int bp = (n == 0) ? -1 : batch[n - 1];
    for (int g = bp + 1; g <= bn; ++g) start[g] = n;
    if (n == N_NODES - 1) {
        for (int g = bn + 1; g <= N_GRAPHS; ++g) start[g] = N_NODES;
    }
}

// ---------- sort-pool (keys cached in LDS) + MLP (f64 accumulate) ----------
__global__ void k_pool_mlp(const float* __restrict__ x, const float* __restrict__ lastc,
                           const int* __restrict__ start,
                           const float* __restrict__ W1, const float* __restrict__ b1,
                           const float* __restrict__ W2, const float* __restrict__ b2,
                           const float* __restrict__ W3, const float* __restrict__ b3,
                           float* __restrict__ out) {
    int g = blockIdx.x;
    int t = threadIdx.x;  // 64 threads = 1 wave
    int s = start[g], e = start[g + 1];
    int cnt = e - s;

    __shared__ ull keys[MAXC];
    __shared__ int sel[KPOOL];
    __shared__ float pl[KPOOL * HDIM];
    __shared__ double part[64];
    __shared__ double h1[HDIM];
    __shared__ double h2[HDIM / 2];

    bool inlds = (cnt <= MAXC);
    if (inlds) {
        for (int i = t; i < cnt; i += 64) {
            int n = s + i;
            keys[i] = ((ull)__float_as_uint(lastc[n]) << 32) | (unsigned int)(~n);
        }
    }
    __syncthreads();

    ull prev = ~0ull;
    for (int k = 0; k < KPOOL; ++k) {
        if (k < cnt) {
            ull best = 0ull;
            if (inlds) {
                for (int i = t; i < cnt; i += 64) {
                    ull key = keys[i];
                    if (key < prev && key > best) best = key;
                }
            } else {
                for (int n = s + t; n < e; n += 64) {
                    ull key = ((ull)__float_as_uint(lastc[n]) << 32) | (unsigned int)(~n);
                    if (key < prev && key > best) best = key;
                }
            }
            for (int off = 32; off; off >>= 1) {
                ull o = __shfl_down(best, off);
                if (o > best) best = o;
            }
            best = __shfl(best, 0);
            prev = best;
            if (t == 0) sel[k] = (int)(~((unsigned int)(best & 0xffffffffull)));
        } else {
            if (t == 0) sel[k] = -1;
        }
    }
    __syncthreads();

    for (int idx = t; idx < KPOOL * HDIM; idx += 64) {
        int k = idx >> 5, c = idx & 31;
        int n = sel[k];
        pl[idx] = (n >= 0) ? x[n * HDIM + c] : 0.0f;
    }
    __syncthreads();

    {
        int j = t & 31;
        int half = t >> 5;
        double acc = 0.0;
        int r0 = half * (KPOOL * HDIM / 2);
        for (int r = r0; r < r0 + KPOOL * HDIM / 2; ++r)
            acc += (double)pl[r] * (double)W1[r * HDIM + j];
        part[t] = acc;
    }
    __syncthreads();
    if (t < HDIM) {
        double v = part[t] + part[t + 32] + (double)b1[t];
        h1[t] = (v > 0.0) ? v : 0.0;
    }
    __syncthreads();

    if (t < HDIM / 2) {
        double a2 = (double)b2[t];
        for (int i = 0; i < HDIM; ++i) a2 += h1[i] * (double)W2[i * (HDIM / 2) + t];
        h2[t] = (a2 > 0.0) ? a2 : 0.0;
    }
    __syncthreads();

    if (t == 0) {
        double o = (double)b3[0];
        for (int i = 0; i < HDIM / 2; ++i) o += h2[i] * (double)W3[i];
        out[g] = (float)o;
    }
}

extern "C" void kernel_launch(void* const* d_in, const int* in_sizes, int n_in,
                              void* d_out, int out_size, void* d_ws, size_t ws_size,
                              hipStream_t stream) {
    const int*   xz    = (const int*)d_in[0];
    const int*   src   = (const int*)d_in[1];            // edge_index[0]
    const int*   dst   = (const int*)d_in[1] + N_EDGES;  // edge_index[1]
    const int*   batch = (const int*)d_in[2];
    const float* emb   = (const float*)d_in[3];
    const float* Wc    = (const float*)d_in[4];
    const float* bc    = (const float*)d_in[5];
    const float* gamma = (const float*)d_in[6];
    const float* beta  = (const float*)d_in[7];
    const float* rmean = (const float*)d_in[8];
    const float* rvar  = (const float*)d_in[9];
    const float* W1    = (const float*)d_in[10];
    const float* b1    = (const float*)d_in[11];
    const float* W2    = (const float*)d_in[12];
    const float* b2    = (const float*)d_in[13];
    const float* W3    = (const float*)d_in[14];
    const float* b3    = (const float*)d_in[15];
    float* out = (float*)d_out;

    // workspace carve-up (256B aligned). Total ~209 MB.
    char* p = (char*)d_ws;
    auto carve = [&](size_t bytes) {
        void* q = (void*)p;
        p += (bytes + 255) & ~size_t(255);
        return q;
    };
    int*   ghist = (int*)carve(HIST_SZ * 4);
    int*   gbase = (int*)carve(HIST_SZ * 4);
    int*   cur   = (int*)carve(HIST_SZ * 4);
    ull*   stage = (ull*)carve((size_t)N_EDGES * 8);
    ull*   csr2  = (ull*)carve((size_t)N_EDGES * 8);
    float* dinv  = (float*)carve(N_NODES * 4);
    int*   offs  = (int*)carve((N_NODES + 1) * 4);
    int*   permB = (int*)carve(N_NODES * 4);
    int*   start = (int*)carve((N_GRAPHS + 1) * 4);
    float* rs    = (float*)carve(NLAYERS * HDIM * 4);
    float* lastc = (float*)carve(N_NODES * 4);
    float* bufA  = (float*)carve((size_t)N_NODES * HDIM * 4);
    float* bufB  = (float*)carve((size_t)N_NODES * HDIM * 4);

    hipMemsetAsync(ghist, 0, HIST_SZ * 4, stream);

    k_hist<<<N_EDGES / 2048, 256, 0, stream>>>(dst, ghist);
    k_scan8k<<<1, 256, 0, stream>>>(ghist, gbase, cur);
    k_bin<<<N_EDGES / 2048, 256, 0, stream>>>(src, dst, cur, stage);
    k_build<<<NBUCKET, 256, 0, stream>>>(stage, gbase, dinv, offs, csr2, permB);
    k_pack<<<N_EDGES / 256, 256, 0, stream>>>(dinv, csr2);
    k_bnprep<<<1, 128, 0, stream>>>(rvar, rs);
    k_starts<<<N_NODES / 256, 256, 0, stream>>>(batch, start);

    const int NG = (N_NODES * HDIM) / 256;
    k_embed_mm<<<NG, 256, 0, stream>>>(xz, emb, Wc + 0 * HDIM * HDIM, bufA);
    k_agg_mm<<<N_NODES / 8, 256, 0, stream>>>(bufA, dinv, offs, csr2, permB,
        bc + 0 * HDIM, rmean + 0 * HDIM, rs + 0 * HDIM, gamma + 0 * HDIM, beta + 0 * HDIM,
        Wc + 1 * HDIM * HDIM, bufB);
    k_agg_mm<<<N_NODES / 8, 256, 0, stream>>>(bufB, dinv, offs, csr2, permB,
        bc + 1 * HDIM, rmean + 1 * HDIM, rs + 1 * HDIM, gamma + 1 * HDIM, beta + 1 * HDIM,
        Wc + 2 * HDIM * HDIM, bufA);
    k_agg_last<<<N_NODES / 8, 256, 0, stream>>>(bufA, dinv, offs, csr2, permB,
        bc + 2 * HDIM, rmean + 2 * HDIM, rs + 2 * HDIM, gamma + 2 * HDIM, beta + 2 * HDIM,
        bufB, lastc);

    k_pool_mlp<<<N_GRAPHS, 64, 0, stream>>>(bufB, lastc, start, W1, b1, W2, b2, W3, b3, out);
}

// Round 12
// 1120.856 us; speedup vs baseline: 1.1393x; 1.0220x over previous
//
#include <hip/hip_runtime.h>
#include <hip/hip_bf16.h>
#include <stdint.h>

#define N_NODES 524288
#define N_EDGES 4194304
#define N_GRAPHS 4096
#define HDIM 32
#define NLAYERS 3
#define KPOOL 30
#define MAXC 1024            // max nodes/graph handled in-LDS in pool (overflow -> fallback)

#define NBUCKET 1024
#define BSHIFT 9             // bucket = dst >> 9
#define NPB 512              // nodes per bucket
#define NCOPY 8              // per-XCD slice copies
#define HIST_SZ (NBUCKET * NCOPY)
#define CAP 6144             // max bucket window held in LDS (mean 4096, sd ~64)

typedef unsigned long long ull;

// Counter arrays are laid out [c][bucket] (c*NBUCKET+b) so each XCD-slice's
// atomics stay in a private 4KB region -- no cross-XCD 64B line ping-pong.
// Scan traversal order remains (b,c)-lexicographic, so the staged edge array
// keeps bucket-major windows: window(b) = [gbase[b], gbase[b+1]) using c=0 entries.

// ---------- histogram of edges per (bucket, xcd-slice) ----------
__global__ void k_hist(const int* __restrict__ dst, int* __restrict__ ghist) {
    __shared__ int lh[NBUCKET];
    int t = threadIdx.x;
    for (int i = t; i < NBUCKET; i += 256) lh[i] = 0;
    __syncthreads();
    int base = blockIdx.x * 2048;
    for (int i = t; i < 2048; i += 256) {
        int d = dst[base + i];
        atomicAdd(&lh[d >> BSHIFT], 1);
    }
    __syncthreads();
    int c = blockIdx.x & 7;
    for (int i = t; i < NBUCKET; i += 256) {
        int v = lh[i];
        if (v) atomicAdd(&ghist[c * NBUCKET + i], v);
    }
}

// ---------- exclusive scan of 8192 counts in (b,c) order -> gbase, cur ----------
__global__ void k_scan8k(const int* __restrict__ ghist, int* __restrict__ gbase,
                         int* __restrict__ cur) {
    __shared__ int tmp[256];
    int t = threadIdx.x;
    int loc[32];
    int s = 0;
    for (int k = 0; k < 32; ++k) {
        int r = t * 32 + k;                    // rank in (b,c) traversal order
        int idx = (r & 7) * NBUCKET + (r >> 3);
        loc[k] = ghist[idx];
        s += loc[k];
    }
    tmp[t] = s;
    __syncthreads();
    for (int d = 1; d < 256; d <<= 1) {
        int a = (t >= d) ? tmp[t - d] : 0;
        __syncthreads();
        tmp[t] += a;
        __syncthreads();
    }
    int run = tmp[t] - s;
    for (int k = 0; k < 32; ++k) {
        int r = t * 32 + k;
        int idx = (r & 7) * NBUCKET + (r >> 3);
        gbase[idx] = run;
        cur[idx] = run;
        run += loc[k];
    }
}

// ---------- bin edges into bucket/slice staging: (src<<32)|(dstLocal<<22)|eid ----------
__global__ void k_bin(const int* __restrict__ src, const int* __restrict__ dst,
                      int* __restrict__ cur, ull* __restrict__ stage) {
    int base = blockIdx.x * 2048;
    int c = blockIdx.x & 7;
    int t = threadIdx.x;
    for (int i = t; i < 2048; i += 256) {
        int e = base + i;
        int d = dst[e];
        int b = d >> BSHIFT;
        int pos = atomicAdd(&cur[c * NBUCKET + b], 1);
        ull rec = ((ull)(unsigned)src[e] << 32)
                | (unsigned)(((d & (NPB - 1)) << 22) | e);
        stage[pos] = rec;
    }
}

// ---------- per-bucket pass 1: counts -> dinv + offs + degree-paired perm ----------
__global__ void k_cnt(const ull* __restrict__ stage, const int* __restrict__ gbase,
                      float* __restrict__ dinv, int* __restrict__ offs,
                      int* __restrict__ perm) {
    __shared__ int cnt[NPB];
    __shared__ int tmp[256];
    int b = blockIdx.x, t = threadIdx.x;
    int s0 = gbase[b];
    int s1 = (b == NBUCKET - 1) ? N_EDGES : gbase[b + 1];
    int win = s1 - s0;
    for (int j = t; j < NPB; j += 256) cnt[j] = 0;
    __syncthreads();
    const unsigned* lo32 = (const unsigned*)stage;
    for (int i = t; i < win; i += 256) {
        unsigned k = lo32[2 * (s0 + i)];
        atomicAdd(&cnt[(k >> 22) & (NPB - 1)], 1);
    }
    __syncthreads();
    int j0 = 2 * t, j1 = 2 * t + 1;
    int a0 = cnt[j0], a1 = cnt[j1];
    {
        // dinv = f32(1 / f32(sqrt(deg+1)))  (identical op sequence to reference)
        float d0 = (float)(a0 + 1);
        float q0 = (float)sqrt((double)d0);
        dinv[b * NPB + j0] = (float)(1.0 / (double)q0);
        float d1 = (float)(a1 + 1);
        float q1 = (float)sqrt((double)d1);
        dinv[b * NPB + j1] = (float)(1.0 / (double)q1);
    }
    int s = a0 + a1;
    tmp[t] = s;
    __syncthreads();
    for (int d = 1; d < 256; d <<= 1) {
        int a = (t >= d) ? tmp[t - d] : 0;
        __syncthreads();
        tmp[t] += a;
        __syncthreads();
    }
    int run = tmp[t] - s;
    offs[b * NPB + j0] = s0 + run;
    offs[b * NPB + j1] = s0 + run + a0;
    if (b == NBUCKET - 1 && t == 255) offs[N_NODES] = N_EDGES;
    __syncthreads();
    // degree-paired schedule: rank nodes by (deg, idx); perm[rank] = node
    for (int jj = 0; jj < 2; ++jj) {
        int j = 2 * t + jj;
        int dj = cnt[j];
        int r = 0;
        for (int k = 0; k < NPB; ++k) {
            int dk = cnt[k];
            r += (dk < dj) || (dk == dj && k < j);
        }
        perm[b * NPB + r] = b * NPB + j;
    }
}

// ---------- per-bucket pass 2: LDS group + eid sort + write-out with dinv pack ----------
__global__ void k_build2(const ull* __restrict__ stage, const int* __restrict__ gbase,
                         const int* __restrict__ offs, const float* __restrict__ dinv,
                         ull* __restrict__ csr2) {
    __shared__ ull grp[CAP];
    __shared__ int sstart[NPB];
    __shared__ int scur[NPB];
    int b = blockIdx.x, t = threadIdx.x;
    int s0 = gbase[b];
    int s1 = (b == NBUCKET - 1) ? N_EDGES : gbase[b + 1];
    int win = s1 - s0;
    for (int j = t; j < NPB; j += 256) {
        int v = offs[b * NPB + j] - s0;
        sstart[j] = v;
        scur[j] = v;
    }
    __syncthreads();

    if (win <= CAP) {
        for (int i = t; i < win; i += 256) {
            ull v = stage[s0 + i];
            unsigned k = (unsigned)v;
            int pos = atomicAdd(&scur[(k >> 22) & (NPB - 1)], 1);
            grp[pos] = v;
        }
        __syncthreads();
        // per-node insertion sort by low word (== eid order within a node)
        for (int jj = 0; jj < 2; ++jj) {
            int j = 2 * t + jj;
            int beg = sstart[j], end = scur[j];
            for (int i = beg + 1; i < end; ++i) {
                ull v = grp[i];
                unsigned kv = (unsigned)v;
                int q = i - 1;
                while (q >= beg && (unsigned)grp[q] > kv) { grp[q + 1] = grp[q]; --q; }
                grp[q + 1] = v;
            }
        }
        __syncthreads();
        // write-out with folded dinv pack (4-deep MLP on the dinv gather)
        int i = t;
        for (; i + 768 < win; i += 1024) {
            ull v0 = grp[i], v1 = grp[i + 256], v2 = grp[i + 512], v3 = grp[i + 768];
            float d0 = dinv[(int)(v0 >> 32)];
            float d1 = dinv[(int)(v1 >> 32)];
            float d2 = dinv[(int)(v2 >> 32)];
            float d3 = dinv[(int)(v3 >> 32)];
            csr2[s0 + i]       = (v0 & 0xffffffff00000000ull) | (unsigned)__float_as_uint(d0);
            csr2[s0 + i + 256] = (v1 & 0xffffffff00000000ull) | (unsigned)__float_as_uint(d1);
            csr2[s0 + i + 512] = (v2 & 0xffffffff00000000ull) | (unsigned)__float_as_uint(d2);
            csr2[s0 + i + 768] = (v3 & 0xffffffff00000000ull) | (unsigned)__float_as_uint(d3);
        }
        for (; i < win; i += 256) {
            ull v = grp[i];
            float dv = dinv[(int)(v >> 32)];
            csr2[s0 + i] = (v & 0xffffffff00000000ull) | (unsigned)__float_as_uint(dv);
        }
    } else {
        // fallback (never triggers for this input): global group + sort + pack
        for (int i = t; i < win; i += 256) {
            ull v = stage[s0 + i];
            unsigned k = (unsigned)v;
            int pos = s0 + atomicAdd(&scur[(k >> 22) & (NPB - 1)], 1);
            csr2[pos] = v;
        }
        __syncthreads();
        for (int jj = 0; jj < 2; ++jj) {
            int j = 2 * t + jj;
            int beg = s0 + sstart[j], end = s0 + scur[j];
            for (int i = beg + 1; i < end; ++i) {
                ull v = csr2[i];
                unsigned kv = (unsigned)v;
                int q = i - 1;
                while (q >= beg && (unsigned)csr2[q] > kv) { csr2[q + 1] = csr2[q]; --q; }
                csr2[q + 1] = v;
            }
        }
        __syncthreads();
        for (int i = t; i < win; i += 256) {
            ull v = csr2[s0 + i];
            float dv = dinv[(int)(v >> 32)];
            csr2[s0 + i] = (v & 0xffffffff00000000ull) | (unsigned)__float_as_uint(dv);
        }
    }
}

// ---------- rs = f32(1 / f32(sqrt(f32(rvar + 1e-5)))) ----------
__global__ void k_bnprep(const float* __restrict__ rvar, float* __restrict__ rs) {
    int i = threadIdx.x;
    if (i < NLAYERS * HDIM) {
        float rv = __fadd_rn(rvar[i], 1e-5f);
        float sq = (float)sqrt((double)rv);
        rs[i] = (float)(1.0 / (double)sq);
    }
}

// ---------- fused embed + matmul layer0 ----------
__global__ void k_embed_mm(const int* __restrict__ xz, const float* __restrict__ emb,
                           const float* __restrict__ Wc, float* __restrict__ h) {
    __shared__ float Wl[HDIM * HDIM];
    __shared__ float xt[256];
    int t = threadIdx.x;
    int base = blockIdx.x * 256;
    for (int i = t; i < HDIM * HDIM; i += 256) Wl[i] = Wc[i];
    {
        int gid = base + t;
        int n = gid >> 5, c = gid & 31;
        xt[t] = emb[xz[n] * HDIM + c];
    }
    __syncthreads();
    int nl = t >> 5, c = t & 31;
    float acc = 0.0f;
#pragma unroll
    for (int k = 0; k < HDIM; ++k) acc = __fmaf_rn(xt[nl * HDIM + k], Wl[k * HDIM + c], acc);
    h[base + t] = acc;
}

// ---------- agg phase: strict f32 op order, 8-deep software pipeline ----------
__device__ __forceinline__ float agg_phase(const float* __restrict__ h,
                                           const float* __restrict__ dinv,
                                           const int* __restrict__ offs,
                                           const ull* __restrict__ csr2,
                                           const float* __restrict__ bc,
                                           const float* __restrict__ rmean,
                                           const float* __restrict__ rs,
                                           const float* __restrict__ gamma,
                                           const float* __restrict__ beta,
                                           int n, int c) {
    float di = dinv[n];
    float hself = h[n * HDIM + c];        // hoisted: overlaps with edge loop
    float accE = 0.0f;  // np.add.at: sequential in edge-id order
    int beg = offs[n], end = offs[n + 1];
    int i = beg;
    for (; i + 8 <= end; i += 8) {
        ull r0 = csr2[i];
        ull r1 = csr2[i + 1];
        ull r2 = csr2[i + 2];
        ull r3 = csr2[i + 3];
        ull r4 = csr2[i + 4];
        ull r5 = csr2[i + 5];
        ull r6 = csr2[i + 6];
        ull r7 = csr2[i + 7];
        float h0 = h[(int)(r0 >> 32) * HDIM + c];
        float h1 = h[(int)(r1 >> 32) * HDIM + c];
        float h2 = h[(int)(r2 >> 32) * HDIM + c];
        float h3 = h[(int)(r3 >> 32) * HDIM + c];
        float h4 = h[(int)(r4 >> 32) * HDIM + c];
        float h5 = h[(int)(r5 >> 32) * HDIM + c];
        float h6 = h[(int)(r6 >> 32) * HDIM + c];
        float h7 = h[(int)(r7 >> 32) * HDIM + c];
        accE = __fadd_rn(accE, __fmul_rn(h0, __fmul_rn(__uint_as_float((unsigned)r0), di)));
        accE = __fadd_rn(accE, __fmul_rn(h1, __fmul_rn(__uint_as_float((unsigned)r1), di)));
        accE = __fadd_rn(accE, __fmul_rn(h2, __fmul_rn(__uint_as_float((unsigned)r2), di)));
        accE = __fadd_rn(accE, __fmul_rn(h3, __fmul_rn(__uint_as_float((unsigned)r3), di)));
        accE = __fadd_rn(accE, __fmul_rn(h4, __fmul_rn(__uint_as_float((unsigned)r4), di)));
        accE = __fadd_rn(accE, __fmul_rn(h5, __fmul_rn(__uint_as_float((unsigned)r5), di)));
        accE = __fadd_rn(accE, __fmul_rn(h6, __fmul_rn(__uint_as_float((unsigned)r6), di)));
        accE = __fadd_rn(accE, __fmul_rn(h7, __fmul_rn(__uint_as_float((unsigned)r7), di)));
    }
    for (; i + 4 <= end; i += 4) {
        ull r0 = csr2[i];
        ull r1 = csr2[i + 1];
        ull r2 = csr2[i + 2];
        ull r3 = csr2[i + 3];
        float h0 = h[(int)(r0 >> 32) * HDIM + c];
        float h1 = h[(int)(r1 >> 32) * HDIM + c];
        float h2 = h[(int)(r2 >> 32) * HDIM + c];
        float h3 = h[(int)(r3 >> 32) * HDIM + c];
        accE = __fadd_rn(accE, __fmul_rn(h0, __fmul_rn(__uint_as_float((unsigned)r0), di)));
        accE = __fadd_rn(accE, __fmul_rn(h1, __fmul_rn(__uint_as_float((unsigned)r1), di)));
        accE = __fadd_rn(accE, __fmul_rn(h2, __fmul_rn(__uint_as_float((unsigned)r2), di)));
        accE = __fadd_rn(accE, __fmul_rn(h3, __fmul_rn(__uint_as_float((unsigned)r3), di)));
    }
    for (; i < end; ++i) {
        ull r = csr2[i];
        float hv = h[(int)(r >> 32) * HDIM + c];
        float dv = __uint_as_float((unsigned)r);
        accE = __fadd_rn(accE, __fmul_rn(hv, __fmul_rn(dv, di)));
    }
    float sn = __fmul_rn(di, di);
    float t1 = __fmul_rn(hself, sn);
    float a2 = __fadd_rn(accE, t1);
    float a3 = __fadd_rn(a2, bc[c]);
    float tt = __fsub_rn(a3, rmean[c]);
    float u  = __fmul_rn(tt, rs[c]);
    float v  = __fmul_rn(u, gamma[c]);
    float xn = __fadd_rn(v, beta[c]);
    return (xn > 0.0f) ? xn : 0.0f;
}

// ---------- fused agg(BN,ReLU) + next-layer matmul, degree-paired schedule ----------
__global__ void k_agg_mm(const float* __restrict__ h, const float* __restrict__ dinv,
                         const int* __restrict__ offs, const ull* __restrict__ csr2,
                         const int* __restrict__ perm,
                         const float* __restrict__ bc, const float* __restrict__ rmean,
                         const float* __restrict__ rs, const float* __restrict__ gamma,
                         const float* __restrict__ beta,
                         const float* __restrict__ Wnext, float* __restrict__ hout) {
    __shared__ float Wl[HDIM * HDIM];
    __shared__ float xt[256];
    __shared__ int nodes[8];
    int t = threadIdx.x;
    for (int i = t; i < HDIM * HDIM; i += 256) Wl[i] = Wnext[i];
    if (t < 8) nodes[t] = perm[blockIdx.x * 8 + t];
    __syncthreads();
    int slot = t >> 5, c = t & 31;
    int n = nodes[slot];
    xt[t] = agg_phase(h, dinv, offs, csr2, bc, rmean, rs, gamma, beta, n, c);
    __syncthreads();
    float acc = 0.0f;
#pragma unroll
    for (int k = 0; k < HDIM; ++k) acc = __fmaf_rn(xt[slot * HDIM + k], Wl[k * HDIM + c], acc);
    hout[n * HDIM + c] = acc;
}

// ---------- last agg: also emit dense channel-31 array for the sort-pool ----------
__global__ void k_agg_last(const float* __restrict__ h, const float* __restrict__ dinv,
                           const int* __restrict__ offs, const ull* __restrict__ csr2,
                           const int* __restrict__ perm,
                           const float* __restrict__ bc, const float* __restrict__ rmean,
                           const float* __restrict__ rs, const float* __restrict__ gamma,
                           const float* __restrict__ beta, float* __restrict__ xout,
                           float* __restrict__ lastc) {
    __shared__ int nodes[8];
    int t = threadIdx.x;
    if (t < 8) nodes[t] = perm[blockIdx.x * 8 + t];
    __syncthreads();
    int slot = t >> 5, c = t & 31;
    int n = nodes[slot];
    float v = agg_phase(h, dinv, offs, csr2, bc, rmean, rs, gamma, beta, n, c);
    xout[n * HDIM + c] = v;
    if (c == 31) lastc[n] = v;
}

// ---------- per-graph starts ----------
__global__ void k_starts(const int* __restrict__ batch, int* __restrict__ start) {
    int n = blockIdx.x * 256 + threadIdx.x;
    if (n >= N_NODES) return;
    int bn = batch[n];
    int bp = (n == 0) ? -1 : batch[n - 1];
    for (int g = bp + 1; g <= bn; ++g) start[g] = n;
    if (n == N_NODES - 1) {
        for (int g = bn + 1; g <= N_GRAPHS; ++g) start[g] = N_NODES;
    }
}

// ---------- sort-pool (keys cached in LDS) + MLP (f64 accumulate) ----------
__global__ void k_pool_mlp(const float* __restrict__ x, const float* __restrict__ lastc,
                           const int* __restrict__ start,
                           const float* __restrict__ W1, const float* __restrict__ b1,
                           const float* __restrict__ W2, const float* __restrict__ b2,
                           const float* __restrict__ W3, const float* __restrict__ b3,
                           float* __restrict__ out) {
    int g = blockIdx.x;
    int t = threadIdx.x;  // 64 threads = 1 wave
    int s = start[g], e = start[g + 1];
    int cnt = e - s;

    __shared__ ull keys[MAXC];
    __shared__ int sel[KPOOL];
    __shared__ float pl[KPOOL * HDIM];
    __shared__ double part[64];
    __shared__ double h1[HDIM];
    __shared__ double h2[HDIM / 2];

    bool inlds = (cnt <= MAXC);
    if (inlds) {
        for (int i = t; i < cnt; i += 64) {
            int n = s + i;
            keys[i] = ((ull)__float_as_uint(lastc[n]) << 32) | (unsigned int)(~n);
        }
    }
    __syncthreads();

    ull prev = ~0ull;
    for (int k = 0; k < KPOOL; ++k) {
        if (k < cnt) {
            ull best = 0ull;
            if (inlds) {
                for (int i = t; i < cnt; i += 64) {
                    ull key = keys[i];
                    if (key < prev && key > best) best = key;
                }
            } else {
                for (int n = s + t; n < e; n += 64) {
                    ull key = ((ull)__float_as_uint(lastc[n]) << 32) | (unsigned int)(~n);
                    if (key < prev && key > best) best = key;
                }
            }
            for (int off = 32; off; off >>= 1) {
                ull o = __shfl_down(best, off);
                if (o > best) best = o;
            }
            best = __shfl(best, 0);
            prev = best;
            if (t == 0) sel[k] = (int)(~((unsigned int)(best & 0xffffffffull)));
        } else {
            if (t == 0) sel[k] = -1;
        }
    }
    __syncthreads();

    for (int idx = t; idx < KPOOL * HDIM; idx += 64) {
        int k = idx >> 5, c = idx & 31;
        int n = sel[k];
        pl[idx] = (n >= 0) ? x[n * HDIM + c] : 0.0f;
    }
    __syncthreads();

    {
        int j = t & 31;
        int half = t >> 5;
        double acc = 0.0;
        int r0 = half * (KPOOL * HDIM / 2);
        for (int r = r0; r < r0 + KPOOL * HDIM / 2; ++r)
            acc += (double)pl[r] * (double)W1[r * HDIM + j];
        part[t] = acc;
    }
    __syncthreads();
    if (t < HDIM) {
        double v = part[t] + part[t + 32] + (double)b1[t];
        h1[t] = (v > 0.0) ? v : 0.0;
    }
    __syncthreads();

    if (t < HDIM / 2) {
        double a2 = (double)b2[t];
        for (int i = 0; i < HDIM; ++i) a2 += h1[i] * (double)W2[i * (HDIM / 2) + t];
        h2[t] = (a2 > 0.0) ? a2 : 0.0;
    }
    __syncthreads();

    if (t == 0) {
        double o = (double)b3[0];
        for (int i = 0; i < HDIM / 2; ++i) o += h2[i] * (double)W3[i];
        out[g] = (float)o;
    }
}

extern "C" void kernel_launch(void* const* d_in, const int* in_sizes, int n_in,
                              void* d_out, int out_size, void* d_ws, size_t ws_size,
                              hipStream_t stream) {
    const int*   xz    = (const int*)d_in[0];
    const int*   src   = (const int*)d_in[1];            // edge_index[0]
    const int*   dst   = (const int*)d_in[1] + N_EDGES;  // edge_index[1]
    const int*   batch = (const int*)d_in[2];
    const float* emb   = (const float*)d_in[3];
    const float* Wc    = (const float*)d_in[4];
    const float* bc    = (const float*)d_in[5];
    const float* gamma = (const float*)d_in[6];
    const float* beta  = (const float*)d_in[7];
    const float* rmean = (const float*)d_in[8];
    const float* rvar  = (const float*)d_in[9];
    const float* W1    = (const float*)d_in[10];
    const float* b1    = (const float*)d_in[11];
    const float* W2    = (const float*)d_in[12];
    const float* b2    = (const float*)d_in[13];
    const float* W3    = (const float*)d_in[14];
    const float* b3    = (const float*)d_in[15];
    float* out = (float*)d_out;

    // workspace carve-up (256B aligned). Total ~209 MB.
    char* p = (char*)d_ws;
    auto carve = [&](size_t bytes) {
        void* q = (void*)p;
        p += (bytes + 255) & ~size_t(255);
        return q;
    };
    int*   ghist = (int*)carve(HIST_SZ * 4);
    int*   gbase = (int*)carve(HIST_SZ * 4);
    int*   cur   = (int*)carve(HIST_SZ * 4);
    ull*   stage = (ull*)carve((size_t)N_EDGES * 8);
    ull*   csr2  = (ull*)carve((size_t)N_EDGES * 8);
    float* dinv  = (float*)carve(N_NODES * 4);
    int*   offs  = (int*)carve((N_NODES + 1) * 4);
    int*   permB = (int*)carve(N_NODES * 4);
    int*   start = (int*)carve((N_GRAPHS + 1) * 4);
    float* rs    = (float*)carve(NLAYERS * HDIM * 4);
    float* lastc = (float*)carve(N_NODES * 4);
    float* bufA  = (float*)carve((size_t)N_NODES * HDIM * 4);
    float* bufB  = (float*)carve((size_t)N_NODES * HDIM * 4);

    hipMemsetAsync(ghist, 0, HIST_SZ * 4, stream);

    k_hist<<<N_EDGES / 2048, 256, 0, stream>>>(dst, ghist);
    k_scan8k<<<1, 256, 0, stream>>>(ghist, gbase, cur);
    k_bin<<<N_EDGES / 2048, 256, 0, stream>>>(src, dst, cur, stage);
    k_cnt<<<NBUCKET, 256, 0, stream>>>(stage, gbase, dinv, offs, permB);
    k_build2<<<NBUCKET, 256, 0, stream>>>(stage, gbase, offs, dinv, csr2);
    k_bnprep<<<1, 128, 0, stream>>>(rvar, rs);
    k_starts<<<N_NODES / 256, 256, 0, stream>>>(batch, start);

    const int NG = (N_NODES * HDIM) / 256;
    k_embed_mm<<<NG, 256, 0, stream>>>(xz, emb, Wc + 0 * HDIM * HDIM, bufA);
    k_agg_mm<<<N_NODES / 8, 256, 0, stream>>>(bufA, dinv, offs, csr2, permB,
        bc + 0 * HDIM, rmean + 0 * HDIM, rs + 0 * HDIM, gamma + 0 * HDIM, beta + 0 * HDIM,
        Wc + 1 * HDIM * HDIM, bufB);
    k_agg_mm<<<N_NODES / 8, 256, 0, stream>>>(bufB, dinv, offs, csr2, permB,
        bc + 1 * HDIM, rmean + 1 * HDIM, rs + 1 * HDIM, gamma + 1 * HDIM, beta + 1 * HDIM,
        Wc + 2 * HDIM * HDIM, bufA);
    k_agg_last<<<N_NODES / 8, 256, 0, stream>>>(bufA, dinv, offs, csr2, permB,
        bc + 2 * HDIM, rmean + 2 * HDIM, rs + 2 * HDIM, gamma + 2 * HDIM, beta + 2 * HDIM,
        bufB, lastc);

    k_pool_mlp<<<N_GRAPHS, 64, 0, stream>>>(bufB, lastc, start, W1, b1, W2, b2, W3, b3, out);
}

// Round 13
// 1032.100 us; speedup vs baseline: 1.2372x; 1.0860x over previous
//
#include <hip/hip_runtime.h>
#include <hip/hip_bf16.h>
#include <stdint.h>

#define N_NODES 524288
#define N_EDGES 4194304
#define N_GRAPHS 4096
#define HDIM 32
#define NLAYERS 3
#define KPOOL 30
#define MAXC 1024            // max nodes/graph handled in-LDS in pool (overflow -> fallback)

#define NBUCKET 1024
#define BSHIFT 9             // bucket = dst >> 9
#define NPB 512              // nodes per bucket
#define NCOPY 8              // per-XCD slice copies
#define HIST_SZ (NBUCKET * NCOPY)
#define CAP 6144             // max bucket window held in LDS (mean 4096, sd ~64)
#define EPB 16384            // edges per histogram/bin block
#define NBIN (N_EDGES / EPB) // 256 blocks

typedef unsigned long long ull;

// Counter arrays are laid out [c][bucket] (c*NBUCKET+b): each XCD-slice's
// atomics stay in a private 4KB region. Scan traversal is (b,c)-lexicographic,
// so bucket b's window = [gbase[b], gbase[b+1]) (c=0 row holds window starts).

// ---------- histogram: per-block counts saved + global [c][bucket] totals ----------
__global__ void k_hist(const int* __restrict__ dst, int* __restrict__ ghist,
                       int* __restrict__ gbh) {
    __shared__ int lh[NBUCKET];
    int t = threadIdx.x;
    for (int i = t; i < NBUCKET; i += 256) lh[i] = 0;
    __syncthreads();
    int base = blockIdx.x * EPB;
    for (int i = t; i < EPB; i += 256) {
        int d = dst[base + i];
        atomicAdd(&lh[d >> BSHIFT], 1);
    }
    __syncthreads();
    int c = blockIdx.x & 7;
    for (int i = t; i < NBUCKET; i += 256) {
        int v = lh[i];
        gbh[blockIdx.x * NBUCKET + i] = v;
        if (v) atomicAdd(&ghist[c * NBUCKET + i], v);
    }
}

// ---------- exclusive scan of 8192 counts in (b,c) order -> gbase, cur ----------
__global__ void k_scan8k(const int* __restrict__ ghist, int* __restrict__ gbase,
                         int* __restrict__ cur) {
    __shared__ int tmp[256];
    int t = threadIdx.x;
    int loc[32];
    int s = 0;
    for (int k = 0; k < 32; ++k) {
        int r = t * 32 + k;                    // rank in (b,c) traversal order
        int idx = (r & 7) * NBUCKET + (r >> 3);
        loc[k] = ghist[idx];
        s += loc[k];
    }
    tmp[t] = s;
    __syncthreads();
    for (int d = 1; d < 256; d <<= 1) {
        int a = (t >= d) ? tmp[t - d] : 0;
        __syncthreads();
        tmp[t] += a;
        __syncthreads();
    }
    int run = tmp[t] - s;
    for (int k = 0; k < 32; ++k) {
        int r = t * 32 + k;
        int idx = (r & 7) * NBUCKET + (r >> 3);
        gbase[idx] = run;
        cur[idx] = run;
        run += loc[k];
    }
}

// ---------- bin: block-aggregated range reservation + LDS-cursor scatter ----------
__global__ void k_bin(const int* __restrict__ src, const int* __restrict__ dst,
                      int* __restrict__ cur, const int* __restrict__ gbh,
                      ull* __restrict__ stage) {
    __shared__ int lbase[NBUCKET];
    __shared__ int lcur[NBUCKET];
    int t = threadIdx.x;
    int c = blockIdx.x & 7;
    for (int i = t; i < NBUCKET; i += 256) {
        int v = gbh[blockIdx.x * NBUCKET + i];
        lbase[i] = v ? atomicAdd(&cur[c * NBUCKET + i], v) : 0;
        lcur[i] = 0;
    }
    __syncthreads();
    int base = blockIdx.x * EPB;
    for (int i = t; i < EPB; i += 256) {
        int e = base + i;
        int d = dst[e];
        int b = d >> BSHIFT;
        int off = atomicAdd(&lcur[b], 1);
        ull rec = ((ull)(unsigned)src[e] << 32)
                | (unsigned)(((d & (NPB - 1)) << 22) | e);
        stage[lbase[b] + off] = rec;
    }
}

// ---------- per-bucket pass 1: counts -> dinv + offs + degree-paired perm ----------
__global__ void k_cnt(const ull* __restrict__ stage, const int* __restrict__ gbase,
                      float* __restrict__ dinv, int* __restrict__ offs,
                      int* __restrict__ perm) {
    __shared__ int cnt[NPB];
    __shared__ int tmp[256];
    int b = blockIdx.x, t = threadIdx.x;
    int s0 = gbase[b];
    int s1 = (b == NBUCKET - 1) ? N_EDGES : gbase[b + 1];
    int win = s1 - s0;
    for (int j = t; j < NPB; j += 256) cnt[j] = 0;
    __syncthreads();
    const unsigned* lo32 = (const unsigned*)stage;
    for (int i = t; i < win; i += 256) {
        unsigned k = lo32[2 * (s0 + i)];
        atomicAdd(&cnt[(k >> 22) & (NPB - 1)], 1);
    }
    __syncthreads();
    int j0 = 2 * t, j1 = 2 * t + 1;
    int a0 = cnt[j0], a1 = cnt[j1];
    {
        // dinv = f32(1 / f32(sqrt(deg+1)))  (identical op sequence to reference)
        float d0 = (float)(a0 + 1);
        float q0 = (float)sqrt((double)d0);
        dinv[b * NPB + j0] = (float)(1.0 / (double)q0);
        float d1 = (float)(a1 + 1);
        float q1 = (float)sqrt((double)d1);
        dinv[b * NPB + j1] = (float)(1.0 / (double)q1);
    }
    int s = a0 + a1;
    tmp[t] = s;
    __syncthreads();
    for (int d = 1; d < 256; d <<= 1) {
        int a = (t >= d) ? tmp[t - d] : 0;
        __syncthreads();
        tmp[t] += a;
        __syncthreads();
    }
    int run = tmp[t] - s;
    offs[b * NPB + j0] = s0 + run;
    offs[b * NPB + j1] = s0 + run + a0;
    if (b == NBUCKET - 1 && t == 255) offs[N_NODES] = N_EDGES;
    __syncthreads();
    // degree-paired schedule: rank nodes by (deg, idx); perm[rank] = node
    for (int jj = 0; jj < 2; ++jj) {
        int j = 2 * t + jj;
        int dj = cnt[j];
        int r = 0;
        for (int k = 0; k < NPB; ++k) {
            int dk = cnt[k];
            r += (dk < dj) || (dk == dj && k < j);
        }
        perm[b * NPB + r] = b * NPB + j;
    }
}

// ---------- per-bucket pass 2: LDS group + eid sort + write-out with dinv pack ----------
__global__ void k_build2(const ull* __restrict__ stage, const int* __restrict__ gbase,
                         const int* __restrict__ offs, const float* __restrict__ dinv,
                         ull* __restrict__ csr2) {
    __shared__ ull grp[CAP];
    __shared__ int sstart[NPB];
    __shared__ int scur[NPB];
    int b = blockIdx.x, t = threadIdx.x;
    int s0 = gbase[b];
    int s1 = (b == NBUCKET - 1) ? N_EDGES : gbase[b + 1];
    int win = s1 - s0;
    for (int j = t; j < NPB; j += 256) {
        int v = offs[b * NPB + j] - s0;
        sstart[j] = v;
        scur[j] = v;
    }
    __syncthreads();

    if (win <= CAP) {
        for (int i = t; i < win; i += 256) {
            ull v = stage[s0 + i];
            unsigned k = (unsigned)v;
            int pos = atomicAdd(&scur[(k >> 22) & (NPB - 1)], 1);
            grp[pos] = v;
        }
        __syncthreads();
        // per-node insertion sort by low word (== eid order within a node)
        for (int jj = 0; jj < 2; ++jj) {
            int j = 2 * t + jj;
            int beg = sstart[j], end = scur[j];
            for (int i = beg + 1; i < end; ++i) {
                ull v = grp[i];
                unsigned kv = (unsigned)v;
                int q = i - 1;
                while (q >= beg && (unsigned)grp[q] > kv) { grp[q + 1] = grp[q]; --q; }
                grp[q + 1] = v;
            }
        }
        __syncthreads();
        // write-out with folded dinv pack (4-deep MLP on the dinv gather)
        int i = t;
        for (; i + 768 < win; i += 1024) {
            ull v0 = grp[i], v1 = grp[i + 256], v2 = grp[i + 512], v3 = grp[i + 768];
            float d0 = dinv[(int)(v0 >> 32)];
            float d1 = dinv[(int)(v1 >> 32)];
            float d2 = dinv[(int)(v2 >> 32)];
            float d3 = dinv[(int)(v3 >> 32)];
            csr2[s0 + i]       = (v0 & 0xffffffff00000000ull) | (unsigned)__float_as_uint(d0);
            csr2[s0 + i + 256] = (v1 & 0xffffffff00000000ull) | (unsigned)__float_as_uint(d1);
            csr2[s0 + i + 512] = (v2 & 0xffffffff00000000ull) | (unsigned)__float_as_uint(d2);
            csr2[s0 + i + 768] = (v3 & 0xffffffff00000000ull) | (unsigned)__float_as_uint(d3);
        }
        for (; i < win; i += 256) {
            ull v = grp[i];
            float dv = dinv[(int)(v >> 32)];
            csr2[s0 + i] = (v & 0xffffffff00000000ull) | (unsigned)__float_as_uint(dv);
        }
    } else {
        // fallback (never triggers for this input): global group + sort + pack
        for (int i = t; i < win; i += 256) {
            ull v = stage[s0 + i];
            unsigned k = (unsigned)v;
            int pos = s0 + atomicAdd(&scur[(k >> 22) & (NPB - 1)], 1);
            csr2[pos] = v;
        }
        __syncthreads();
        for (int jj = 0; jj < 2; ++jj) {
            int j = 2 * t + jj;
            int beg = s0 + sstart[j], end = s0 + scur[j];
            for (int i = beg + 1; i < end; ++i) {
                ull v = csr2[i];
                unsigned kv = (unsigned)v;
                int q = i - 1;
                while (q >= beg && (unsigned)csr2[q] > kv) { csr2[q + 1] = csr2[q]; --q; }
                csr2[q + 1] = v;
            }
        }
        __syncthreads();
        for (int i = t; i < win; i += 256) {
            ull v = csr2[s0 + i];
            float dv = dinv[(int)(v >> 32)];
            csr2[s0 + i] = (v & 0xffffffff00000000ull) | (unsigned)__float_as_uint(dv);
        }
    }
}

// ---------- rs = f32(1 / f32(sqrt(f32(rvar + 1e-5)))) ----------
__global__ void k_bnprep(const float* __restrict__ rvar, float* __restrict__ rs) {
    int i = threadIdx.x;
    if (i < NLAYERS * HDIM) {
        float rv = __fadd_rn(rvar[i], 1e-5f);
        float sq = (float)sqrt((double)rv);
        rs[i] = (float)(1.0 / (double)sq);
    }
}

// ---------- fused embed + matmul layer0 ----------
__global__ void k_embed_mm(const int* __restrict__ xz, const float* __restrict__ emb,
                           const float* __restrict__ Wc, float* __restrict__ h) {
    __shared__ float Wl[HDIM * HDIM];
    __shared__ float xt[256];
    int t = threadIdx.x;
    int base = blockIdx.x * 256;
    for (int i = t; i < HDIM * HDIM; i += 256) Wl[i] = Wc[i];
    {
        int gid = base + t;
        int n = gid >> 5, c = gid & 31;
        xt[t] = emb[xz[n] * HDIM + c];
    }
    __syncthreads();
    int nl = t >> 5, c = t & 31;
    float acc = 0.0f;
#pragma unroll
    for (int k = 0; k < HDIM; ++k) acc = __fmaf_rn(xt[nl * HDIM + k], Wl[k * HDIM + c], acc);
    h[base + t] = acc;
}

// ---------- agg phase: strict f32 op order, 8-deep software pipeline ----------
__device__ __forceinline__ float agg_phase(const float* __restrict__ h,
                                           const float* __restrict__ dinv,
                                           const int* __restrict__ offs,
                                           const ull* __restrict__ csr2,
                                           const float* __restrict__ bc,
                                           const float* __restrict__ rmean,
                                           const float* __restrict__ rs,
                                           const float* __restrict__ gamma,
                                           const float* __restrict__ beta,
                                           int n, int c) {
    float di = dinv[n];
    float hself = h[n * HDIM + c];        // hoisted: overlaps with edge loop
    float accE = 0.0f;  // np.add.at: sequential in edge-id order
    int beg = offs[n], end = offs[n + 1];
    int i = beg;
    for (; i + 8 <= end; i += 8) {
        ull r0 = csr2[i];
        ull r1 = csr2[i + 1];
        ull r2 = csr2[i + 2];
        ull r3 = csr2[i + 3];
        ull r4 = csr2[i + 4];
        ull r5 = csr2[i + 5];
        ull r6 = csr2[i + 6];
        ull r7 = csr2[i + 7];
        float h0 = h[(int)(r0 >> 32) * HDIM + c];
        float h1 = h[(int)(r1 >> 32) * HDIM + c];
        float h2 = h[(int)(r2 >> 32) * HDIM + c];
        float h3 = h[(int)(r3 >> 32) * HDIM + c];
        float h4 = h[(int)(r4 >> 32) * HDIM + c];
        float h5 = h[(int)(r5 >> 32) * HDIM + c];
        float h6 = h[(int)(r6 >> 32) * HDIM + c];
        float h7 = h[(int)(r7 >> 32) * HDIM + c];
        accE = __fadd_rn(accE, __fmul_rn(h0, __fmul_rn(__uint_as_float((unsigned)r0), di)));
        accE = __fadd_rn(accE, __fmul_rn(h1, __fmul_rn(__uint_as_float((unsigned)r1), di)));
        accE = __fadd_rn(accE, __fmul_rn(h2, __fmul_rn(__uint_as_float((unsigned)r2), di)));
        accE = __fadd_rn(accE, __fmul_rn(h3, __fmul_rn(__uint_as_float((unsigned)r3), di)));
        accE = __fadd_rn(accE, __fmul_rn(h4, __fmul_rn(__uint_as_float((unsigned)r4), di)));
        accE = __fadd_rn(accE, __fmul_rn(h5, __fmul_rn(__uint_as_float((unsigned)r5), di)));
        accE = __fadd_rn(accE, __fmul_rn(h6, __fmul_rn(__uint_as_float((unsigned)r6), di)));
        accE = __fadd_rn(accE, __fmul_rn(h7, __fmul_rn(__uint_as_float((unsigned)r7), di)));
    }
    for (; i + 4 <= end; i += 4) {
        ull r0 = csr2[i];
        ull r1 = csr2[i + 1];
        ull r2 = csr2[i + 2];
        ull r3 = csr2[i + 3];
        float h0 = h[(int)(r0 >> 32) * HDIM + c];
        float h1 = h[(int)(r1 >> 32) * HDIM + c];
        float h2 = h[(int)(r2 >> 32) * HDIM + c];
        float h3 = h[(int)(r3 >> 32) * HDIM + c];
        accE = __fadd_rn(accE, __fmul_rn(h0, __fmul_rn(__uint_as_float((unsigned)r0), di)));
        accE = __fadd_rn(accE, __fmul_rn(h1, __fmul_rn(__uint_as_float((unsigned)r1), di)));
        accE = __fadd_rn(accE, __fmul_rn(h2, __fmul_rn(__uint_as_float((unsigned)r2), di)));
        accE = __fadd_rn(accE, __fmul_rn(h3, __fmul_rn(__uint_as_float((unsigned)r3), di)));
    }
    for (; i < end; ++i) {
        ull r = csr2[i];
        float hv = h[(int)(r >> 32) * HDIM + c];
        float dv = __uint_as_float((unsigned)r);
        accE = __fadd_rn(accE, __fmul_rn(hv, __fmul_rn(dv, di)));
    }
    float sn = __fmul_rn(di, di);
    float t1 = __fmul_rn(hself, sn);
    float a2 = __fadd_rn(accE, t1);
    float a3 = __fadd_rn(a2, bc[c]);
    float tt = __fsub_rn(a3, rmean[c]);
    float u  = __fmul_rn(tt, rs[c]);
    float v  = __fmul_rn(u, gamma[c]);
    float xn = __fadd_rn(v, beta[c]);
    return (xn > 0.0f) ? xn : 0.0f;
}

// ---------- fused agg(BN,ReLU) + next-layer matmul, degree-paired schedule ----------
__global__ void k_agg_mm(const float* __restrict__ h, const float* __restrict__ dinv,
                         const int* __restrict__ offs, const ull* __restrict__ csr2,
                         const int* __restrict__ perm,
                         const float* __restrict__ bc, const float* __restrict__ rmean,
                         const float* __restrict__ rs, const float* __restrict__ gamma,
                         const float* __restrict__ beta,
                         const float* __restrict__ Wnext, float* __restrict__ hout) {
    __shared__ float Wl[HDIM * HDIM];
    __shared__ float xt[256];
    __shared__ int nodes[8];
    int t = threadIdx.x;
    for (int i = t; i < HDIM * HDIM; i += 256) Wl[i] = Wnext[i];
    if (t < 8) nodes[t] = perm[blockIdx.x * 8 + t];
    __syncthreads();
    int slot = t >> 5, c = t & 31;
    int n = nodes[slot];
    xt[t] = agg_phase(h, dinv, offs, csr2, bc, rmean, rs, gamma, beta, n, c);
    __syncthreads();
    float acc = 0.0f;
#pragma unroll
    for (int k = 0; k < HDIM; ++k) acc = __fmaf_rn(xt[slot * HDIM + k], Wl[k * HDIM + c], acc);
    hout[n * HDIM + c] = acc;
}

// ---------- last agg: also emit dense channel-31 array for the sort-pool ----------
__global__ void k_agg_last(const float* __restrict__ h, const float* __restrict__ dinv,
                           const int* __restrict__ offs, const ull* __restrict__ csr2,
                           const int* __restrict__ perm,
                           const float* __restrict__ bc, const float* __restrict__ rmean,
                           const float* __restrict__ rs, const float* __restrict__ gamma,
                           const float* __restrict__ beta, float* __restrict__ xout,
                           float* __restrict__ lastc) {
    __shared__ int nodes[8];
    int t = threadIdx.x;
    if (t < 8) nodes[t] = perm[blockIdx.x * 8 + t];
    __syncthreads();
    int slot = t >> 5, c = t & 31;
    int n = nodes[slot];
    float v = agg_phase(h, dinv, offs, csr2, bc, rmean, rs, gamma, beta, n, c);
    xout[n * HDIM + c] = v;
    if (c == 31) lastc[n] = v;
}

// ---------- per-graph starts ----------
__global__ void k_starts(const int* __restrict__ batch, int* __restrict__ start) {
    int n = blockIdx.x * 256 + threadIdx.x;
    if (n >= N_NODES) return;
    int bn = batch[n];
    int bp = (n == 0) ? -1 : batch[n - 1];
    for (int g = bp + 1; g <= bn; ++g) start[g] = n;
    if (n == N_NODES - 1) {
        for (int g = bn + 1; g <= N_GRAPHS; ++g) start[g] = N_NODES;
    }
}

// ---------- sort-pool (keys cached in LDS) + MLP (f64 accumulate) ----------
__global__ void k_pool_mlp(const float* __restrict__ x, const float* __restrict__ lastc,
                           const int* __restrict__ start,
                           const float* __restrict__ W1, const float* __restrict__ b1,
                           const float* __restrict__ W2, const float* __restrict__ b2,
                           const float* __restrict__ W3, const float* __restrict__ b3,
                           float* __restrict__ out) {
    int g = blockIdx.x;
    int t = threadIdx.x;  // 64 threads = 1 wave
    int s = start[g], e = start[g + 1];
    int cnt = e - s;

    __shared__ ull keys[MAXC];
    __shared__ int sel[KPOOL];
    __shared__ float pl[KPOOL * HDIM];
    __shared__ double part[64];
    __shared__ double h1[HDIM];
    __shared__ double h2[HDIM / 2];

    bool inlds = (cnt <= MAXC);
    if (inlds) {
        for (int i = t; i < cnt; i += 64) {
            int n = s + i;
            keys[i] = ((ull)__float_as_uint(lastc[n]) << 32) | (unsigned int)(~n);
        }
    }
    __syncthreads();

    ull prev = ~0ull;
    for (int k = 0; k < KPOOL; ++k) {
        if (k < cnt) {
            ull best = 0ull;
            if (inlds) {
                for (int i = t; i < cnt; i += 64) {
                    ull key = keys[i];
                    if (key < prev && key > best) best = key;
                }
            } else {
                for (int n = s + t; n < e; n += 64) {
                    ull key = ((ull)__float_as_uint(lastc[n]) << 32) | (unsigned int)(~n);
                    if (key < prev && key > best) best = key;
                }
            }
            for (int off = 32; off; off >>= 1) {
                ull o = __shfl_down(best, off);
                if (o > best) best = o;
            }
            best = __shfl(best, 0);
            prev = best;
            if (t == 0) sel[k] = (int)(~((unsigned int)(best & 0xffffffffull)));
        } else {
            if (t == 0) sel[k] = -1;
        }
    }
    __syncthreads();

    for (int idx = t; idx < KPOOL * HDIM; idx += 64) {
        int k = idx >> 5, c = idx & 31;
        int n = sel[k];
        pl[idx] = (n >= 0) ? x[n * HDIM + c] : 0.0f;
    }
    __syncthreads();

    {
        int j = t & 31;
        int half = t >> 5;
        double acc = 0.0;
        int r0 = half * (KPOOL * HDIM / 2);
        for (int r = r0; r < r0 + KPOOL * HDIM / 2; ++r)
            acc += (double)pl[r] * (double)W1[r * HDIM + j];
        part[t] = acc;
    }
    __syncthreads();
    if (t < HDIM) {
        double v = part[t] + part[t + 32] + (double)b1[t];
        h1[t] = (v > 0.0) ? v : 0.0;
    }
    __syncthreads();

    if (t < HDIM / 2) {
        double a2 = (double)b2[t];
        for (int i = 0; i < HDIM; ++i) a2 += h1[i] * (double)W2[i * (HDIM / 2) + t];
        h2[t] = (a2 > 0.0) ? a2 : 0.0;
    }
    __syncthreads();

    if (t == 0) {
        double o = (double)b3[0];
        for (int i = 0; i < HDIM / 2; ++i) o += h2[i] * (double)W3[i];
        out[g] = (float)o;
    }
}

extern "C" void kernel_launch(void* const* d_in, const int* in_sizes, int n_in,
                              void* d_out, int out_size, void* d_ws, size_t ws_size,
                              hipStream_t stream) {
    const int*   xz    = (const int*)d_in[0];
    const int*   src   = (const int*)d_in[1];            // edge_index[0]
    const int*   dst   = (const int*)d_in[1] + N_EDGES;  // edge_index[1]
    const int*   batch = (const int*)d_in[2];
    const float* emb   = (const float*)d_in[3];
    const float* Wc    = (const float*)d_in[4];
    const float* bc    = (const float*)d_in[5];
    const float* gamma = (const float*)d_in[6];
    const float* beta  = (const float*)d_in[7];
    const float* rmean = (const float*)d_in[8];
    const float* rvar  = (const float*)d_in[9];
    const float* W1    = (const float*)d_in[10];
    const float* b1    = (const float*)d_in[11];
    const float* W2    = (const float*)d_in[12];
    const float* b2    = (const float*)d_in[13];
    const float* W3    = (const float*)d_in[14];
    const float* b3    = (const float*)d_in[15];
    float* out = (float*)d_out;

    // workspace carve-up (256B aligned). Total ~210 MB.
    char* p = (char*)d_ws;
    auto carve = [&](size_t bytes) {
        void* q = (void*)p;
        p += (bytes + 255) & ~size_t(255);
        return q;
    };
    int*   ghist = (int*)carve(HIST_SZ * 4);
    int*   gbase = (int*)carve(HIST_SZ * 4);
    int*   cur   = (int*)carve(HIST_SZ * 4);
    int*   gbh   = (int*)carve((size_t)NBIN * NBUCKET * 4);
    ull*   stage = (ull*)carve((size_t)N_EDGES * 8);
    ull*   csr2  = (ull*)carve((size_t)N_EDGES * 8);
    float* dinv  = (float*)carve(N_NODES * 4);
    int*   offs  = (int*)carve((N_NODES + 1) * 4);
    int*   permB = (int*)carve(N_NODES * 4);
    int*   start = (int*)carve((N_GRAPHS + 1) * 4);
    float* rs    = (float*)carve(NLAYERS * HDIM * 4);
    float* lastc = (float*)carve(N_NODES * 4);
    float* bufA  = (float*)carve((size_t)N_NODES * HDIM * 4);
    float* bufB  = (float*)carve((size_t)N_NODES * HDIM * 4);

    hipMemsetAsync(ghist, 0, HIST_SZ * 4, stream);

    k_hist<<<NBIN, 256, 0, stream>>>(dst, ghist, gbh);
    k_scan8k<<<1, 256, 0, stream>>>(ghist, gbase, cur);
    k_bin<<<NBIN, 256, 0, stream>>>(src, dst, cur, gbh, stage);
    k_cnt<<<NBUCKET, 256, 0, stream>>>(stage, gbase, dinv, offs, permB);
    k_build2<<<NBUCKET, 256, 0, stream>>>(stage, gbase, offs, dinv, csr2);
    k_bnprep<<<1, 128, 0, stream>>>(rvar, rs);
    k_starts<<<N_NODES / 256, 256, 0, stream>>>(batch, start);

    const int NG = (N_NODES * HDIM) / 256;
    k_embed_mm<<<NG, 256, 0, stream>>>(xz, emb, Wc + 0 * HDIM * HDIM, bufA);
    k_agg_mm<<<N_NODES / 8, 256, 0, stream>>>(bufA, dinv, offs, csr2, permB,
        bc + 0 * HDIM, rmean + 0 * HDIM, rs + 0 * HDIM, gamma + 0 * HDIM, beta + 0 * HDIM,
        Wc + 1 * HDIM * HDIM, bufB);
    k_agg_mm<<<N_NODES / 8, 256, 0, stream>>>(bufB, dinv, offs, csr2, permB,
        bc + 1 * HDIM, rmean + 1 * HDIM, rs + 1 * HDIM, gamma + 1 * HDIM, beta + 1 * HDIM,
        Wc + 2 * HDIM * HDIM, bufA);
    k_agg_last<<<N_NODES / 8, 256, 0, stream>>>(bufA, dinv, offs, csr2, permB,
        bc + 2 * HDIM, rmean + 2 * HDIM, rs + 2 * HDIM, gamma + 2 * HDIM, beta + 2 * HDIM,
        bufB, lastc);

    k_pool_mlp<<<N_GRAPHS, 64, 0, stream>>>(bufB, lastc, start, W1, b1, W2, b2, W3, b3, out);
}